// Round 1
// baseline (994.565 us; speedup 1.0000x reference)
//
#include <hip/hip_runtime.h>
#include <hip/hip_bf16.h>
#include <cstdint>

// Problem constants (fixed by setup_inputs)
#define BB 2
#define SS 192
#define HH 768
#define NHH 8
#define DHH 96
#define H4 3072
#define NJ 383          // used pe rows: idx in [321, 703]
#define NJP 384
#define JOFF 321
#define ATT_SCALE 0.10206207261596575f   // 1/sqrt(96)

using bf16 = __hip_bfloat16;

__device__ __forceinline__ float bflo(unsigned u){ return __uint_as_float(u << 16); }
__device__ __forceinline__ float bfhi(unsigned u){ return __uint_as_float(u & 0xffff0000u); }

// ---------------- x = a + b (elementwise, float4) ----------------
__global__ __launch_bounds__(256) void add_kernel(const float4* __restrict__ a,
    const float4* __restrict__ b, float4* __restrict__ o, int n4) {
  int i = blockIdx.x * 256 + threadIdx.x;
  if (i < n4) {
    float4 va = a[i], vb = b[i];
    o[i] = make_float4(va.x + vb.x, va.y + vb.y, va.z + vb.z, va.w + vb.w);
  }
}

// ---------------- generic f32 GEMM: C[M,N] = A[M,K]@B[K,N] (+bias)(relu)(bf16 out) ----
// Requires N%64==0, K%16==0. M arbitrary (row-guarded).
template<bool OUT_BF16, bool RELU>
__global__ __launch_bounds__(256) void gemm_f32(const float* __restrict__ A,
    const float* __restrict__ Bm, const float* __restrict__ bias,
    void* __restrict__ Cv, int M, int N, int K) {
  __shared__ float As[16][64];
  __shared__ float Bs[16][64];
  const int t = threadIdx.x;
  const int tx = t & 15, ty = t >> 4;
  const int bm = blockIdx.y * 64, bn = blockIdx.x * 64;
  const int arow = t >> 2, acol = (t & 3) << 2;
  const int brow = t >> 4, bcol = (t & 15) << 2;
  float acc[4][4] = {};
  for (int kt = 0; kt < K; kt += 16) {
    float4 av = make_float4(0.f, 0.f, 0.f, 0.f);
    if (bm + arow < M) av = *(const float4*)(A + (size_t)(bm + arow) * K + kt + acol);
    As[acol + 0][arow] = av.x; As[acol + 1][arow] = av.y;
    As[acol + 2][arow] = av.z; As[acol + 3][arow] = av.w;
    *(float4*)&Bs[brow][bcol] = *(const float4*)(Bm + (size_t)(kt + brow) * N + bn + bcol);
    __syncthreads();
#pragma unroll
    for (int kk = 0; kk < 16; ++kk) {
      const float4 a = *(const float4*)&As[kk][ty << 2];
      const float4 b = *(const float4*)&Bs[kk][tx << 2];
      acc[0][0] += a.x * b.x; acc[0][1] += a.x * b.y; acc[0][2] += a.x * b.z; acc[0][3] += a.x * b.w;
      acc[1][0] += a.y * b.x; acc[1][1] += a.y * b.y; acc[1][2] += a.y * b.z; acc[1][3] += a.y * b.w;
      acc[2][0] += a.z * b.x; acc[2][1] += a.z * b.y; acc[2][2] += a.z * b.z; acc[2][3] += a.z * b.w;
      acc[3][0] += a.w * b.x; acc[3][1] += a.w * b.y; acc[3][2] += a.w * b.z; acc[3][3] += a.w * b.w;
    }
    __syncthreads();
  }
#pragma unroll
  for (int i = 0; i < 4; ++i) {
    const int row = bm + (ty << 2) + i;
    if (row >= M) break;
#pragma unroll
    for (int j = 0; j < 4; ++j) {
      const int col = bn + (tx << 2) + j;
      float v = acc[i][j];
      if (bias) v += bias[col];
      if (RELU) v = fmaxf(v, 0.f);
      if (OUT_BF16) ((bf16*)Cv)[(size_t)row * N + col] = __float2bfloat16(v);
      else          ((float*)Cv)[(size_t)row * N + col] = v;
    }
  }
}

// ---------------- G[b,n,q,j] = dot(q[b,q,n,:]+v[n,:], PRb[j,n,:]) ----------------
__global__ __launch_bounds__(128) void g_kernel(const float* __restrict__ qb,
    const float* __restrict__ PRb, const float* __restrict__ vbias, float* __restrict__ G) {
  const int idx = blockIdx.x;                   // (b*8+n)*192 + q
  const int qq = idx % SS; const int bn = idx / SS;
  const int n = bn & 7; const int b = bn >> 3;
  __shared__ float qu[DHH];
  const int t = threadIdx.x;
  if (t < DHH) qu[t] = qb[(size_t)(b * SS + qq) * HH + n * DHH + t] + vbias[n * DHH + t];
  __syncthreads();
  for (int j = t; j < NJ; j += 128) {
    const float* pr = PRb + (size_t)j * HH + n * DHH;
    float s = 0.f;
#pragma unroll
    for (int d = 0; d < DHH; d += 4) {
      const float4 pv = *(const float4*)(pr + d);
      const float4 qv = *(const float4*)(qu + d);
      s += qv.x * pv.x + qv.y * pv.y + qv.z * pv.z + qv.w * pv.w;
    }
    G[(size_t)idx * NJP + j] = s;
  }
}

// ---------------- per-(b,q,k) pair kernel: w4 softmax + BD scores ----------------
// One wave per pair, 16 pairs per wave, 4 waves per block.
__global__ __launch_bounds__(256) void pair_kernel(const bf16* __restrict__ Tt,
    const float* __restrict__ bf1, const float* __restrict__ wf2, const float* __restrict__ bf2,
    const int* __restrict__ pos_s, const int* __restrict__ pos_e,
    const float* __restrict__ G, float* __restrict__ att) {
  __shared__ float wf2t[4 * H4];   // transposed: [f][c]
  __shared__ float bf1s[H4];
  for (int i = threadIdx.x; i < 4 * H4; i += 256)
    wf2t[(i & 3) * H4 + (i >> 2)] = wf2[i];
  for (int i = threadIdx.x; i < H4; i += 256) bf1s[i] = bf1[i];
  __syncthreads();
  const float b2r0 = bf2[0], b2r1 = bf2[1], b2r2 = bf2[2], b2r3 = bf2[3];
  const int wave = threadIdx.x >> 6, lane = threadIdx.x & 63;
  const int pbase = blockIdx.x * 64 + wave * 16;
  for (int it = 0; it < 16; ++it) {
    const int p = pbase + it;
    const int b = p / (SS * SS);
    const int rem = p - b * (SS * SS);
    const int qq = rem / SS;
    const int kk = rem - qq * SS;
    const int psq = pos_s[b * SS + qq], peq = pos_e[b * SS + qq];
    const int psk = pos_s[b * SS + kk], pek = pos_e[b * SS + kk];
    const int j0 = min(max(psq - psk + 512 - JOFF, 0), NJ - 1);
    const int j1 = min(max(psq - pek + 512 - JOFF, 0), NJ - 1);
    const int j2 = min(max(peq - psk + 512 - JOFF, 0), NJ - 1);
    const int j3 = min(max(peq - pek + 512 - JOFF, 0), NJ - 1);
    const unsigned* t0 = (const unsigned*)Tt + (size_t)j0 * (H4 / 2);
    const unsigned* t1 = (const unsigned*)Tt + (size_t)(NJP + j1) * (H4 / 2);
    const unsigned* t2 = (const unsigned*)Tt + (size_t)(2 * NJP + j2) * (H4 / 2);
    const unsigned* t3 = (const unsigned*)Tt + (size_t)(3 * NJP + j3) * (H4 / 2);
    float a0 = 0.f, a1 = 0.f, a2 = 0.f, a3 = 0.f;
#pragma unroll 6
    for (int m = 0; m < 24; ++m) {
      const int cw = lane + (m << 6);        // dword index; covers bf16 pair c=2cw, 2cw+1
      const unsigned u0 = t0[cw], u1 = t1[cw], u2 = t2[cw], u3 = t3[cw];
      const int c = cw << 1;
      float s0 = bflo(u0) + bflo(u1) + bflo(u2) + bflo(u3) + bf1s[c];
      float s1 = bfhi(u0) + bfhi(u1) + bfhi(u2) + bfhi(u3) + bf1s[c + 1];
      s0 = fmaxf(s0, 0.f); s1 = fmaxf(s1, 0.f);
      a0 += s0 * wf2t[c]          + s1 * wf2t[c + 1];
      a1 += s0 * wf2t[H4 + c]     + s1 * wf2t[H4 + c + 1];
      a2 += s0 * wf2t[2 * H4 + c] + s1 * wf2t[2 * H4 + c + 1];
      a3 += s0 * wf2t[3 * H4 + c] + s1 * wf2t[3 * H4 + c + 1];
    }
#pragma unroll
    for (int off = 32; off > 0; off >>= 1) {
      a0 += __shfl_xor(a0, off, 64);
      a1 += __shfl_xor(a1, off, 64);
      a2 += __shfl_xor(a2, off, 64);
      a3 += __shfl_xor(a3, off, 64);
    }
    a0 += b2r0; a1 += b2r1; a2 += b2r2; a3 += b2r3;
    const float mx = fmaxf(fmaxf(a0, a1), fmaxf(a2, a3));
    const float e0 = __expf(a0 - mx), e1 = __expf(a1 - mx);
    const float e2 = __expf(a2 - mx), e3 = __expf(a3 - mx);
    const float inv = 1.f / (e0 + e1 + e2 + e3);
    // BD[b,n,q,k] = sum_f w4[f] * G[b,n,q,j_f]; lanes 0..31: n=lane>>2, f=lane&3
    const int n = (lane >> 2) & 7, f = lane & 3;
    const int jf = (f == 0) ? j0 : (f == 1) ? j1 : (f == 2) ? j2 : j3;
    const float wsel = ((f == 0) ? e0 : (f == 1) ? e1 : (f == 2) ? e2 : e3) * inv;
    float g = wsel * G[(size_t)((b * NHH + n) * SS + qq) * NJP + jf];
    g += __shfl_xor(g, 1, 64);
    g += __shfl_xor(g, 2, 64);
    if (lane < 32 && (lane & 3) == 0)
      att[(size_t)((b * NHH + n) * SS + qq) * SS + kk] = g;
  }
}

// ---------------- attention: att = softmax_k((AC+BD)*scale + mask) ----------------
__global__ __launch_bounds__(256) void attn_kernel(const float* __restrict__ qb,
    const float* __restrict__ kb, const float* __restrict__ u,
    const int* __restrict__ seq_len, const int* __restrict__ lex_num,
    float* __restrict__ att) {
  const int idx = blockIdx.x;                  // (b*8+n)*192 + q
  const int qq = idx % SS; const int bn = idx / SS;
  const int n = bn & 7; const int b = bn >> 3;
  __shared__ float qu[DHH];
  __shared__ float red[256];
  const int t = threadIdx.x;
  if (t < DHH) qu[t] = qb[(size_t)(b * SS + qq) * HH + n * DHH + t] + u[n * DHH + t];
  __syncthreads();
  const int vbnd = seq_len[b] + lex_num[b];
  float val = -3.0e38f;
  if (t < SS) {
    const float* kr = kb + (size_t)(b * SS + t) * HH + n * DHH;
    float ac = 0.f;
#pragma unroll
    for (int d = 0; d < DHH; d += 4) {
      const float4 kv = *(const float4*)(kr + d);
      const float4 qv = *(const float4*)(qu + d);
      ac += qv.x * kv.x + qv.y * kv.y + qv.z * kv.z + qv.w * kv.w;
    }
    val = (ac + att[(size_t)idx * SS + t]) * ATT_SCALE;
    if (t >= vbnd) val = -1e15f;
  }
  red[t] = val; __syncthreads();
  for (int s = 128; s > 0; s >>= 1) { if (t < s) red[t] = fmaxf(red[t], red[t + s]); __syncthreads(); }
  const float mx = red[0]; __syncthreads();
  const float e = (t < SS) ? __expf(val - mx) : 0.f;
  red[t] = e; __syncthreads();
  for (int s = 128; s > 0; s >>= 1) { if (t < s) red[t] += red[t + s]; __syncthreads(); }
  const float inv = 1.f / red[0];
  if (t < SS) att[(size_t)idx * SS + t] = e * inv;
}

// ---------------- ctx[b,q,:] = sum_k pattn[b,n,q,k] * v[b,k,n,:] ----------------
__global__ __launch_bounds__(256) void ctx_kernel(const float* __restrict__ att,
    const float* __restrict__ vb, float* __restrict__ ctx) {
  const int idx = blockIdx.x;                  // b*192 + q
  const int qq = idx % SS, b = idx / SS;
  __shared__ float ps[NHH * SS];
  const int t = threadIdx.x;
  for (int i = t; i < NHH * SS; i += 256) {
    const int n = i / SS, k = i - n * SS;
    ps[i] = att[(size_t)((b * NHH + n) * SS + qq) * SS + k];
  }
  __syncthreads();
#pragma unroll
  for (int rep = 0; rep < 3; ++rep) {
    const int o = t + rep * 256;
    const int n = o / DHH;
    const float* vp = vb + (size_t)b * SS * HH + o;
    const float* pp = ps + n * SS;
    float acc = 0.f;
#pragma unroll 4
    for (int k = 0; k < SS; ++k) acc += pp[k] * vp[(size_t)k * HH];
    ctx[(size_t)idx * HH + o] = acc;
  }
}

// ---------------- out = LayerNorm(xin + dres) * g + b ----------------
__global__ __launch_bounds__(256) void ln_kernel(const float* __restrict__ xin,
    const float* __restrict__ dres, const float* __restrict__ g,
    const float* __restrict__ bta, float* __restrict__ out) {
  const int row = blockIdx.x;
  const int t = threadIdx.x;
  __shared__ float red[256];
  const size_t base = (size_t)row * HH;
  const float v0 = xin[base + t] + dres[base + t];
  const float v1 = xin[base + 256 + t] + dres[base + 256 + t];
  const float v2 = xin[base + 512 + t] + dres[base + 512 + t];
  red[t] = v0 + v1 + v2; __syncthreads();
  for (int s = 128; s > 0; s >>= 1) { if (t < s) red[t] += red[t + s]; __syncthreads(); }
  const float mean = red[0] * (1.f / 768.f); __syncthreads();
  red[t] = v0 * v0 + v1 * v1 + v2 * v2; __syncthreads();
  for (int s = 128; s > 0; s >>= 1) { if (t < s) red[t] += red[t + s]; __syncthreads(); }
  const float var = red[0] * (1.f / 768.f) - mean * mean;
  const float rstd = rsqrtf(var + 1e-5f);
  out[base + t]       = (v0 - mean) * rstd * g[t]       + bta[t];
  out[base + 256 + t] = (v1 - mean) * rstd * g[256 + t] + bta[256 + t];
  out[base + 512 + t] = (v2 - mean) * rstd * g[512 + t] + bta[512 + t];
}

extern "C" void kernel_launch(void* const* d_in, const int* in_sizes, int n_in,
                              void* d_out, int out_size, void* d_ws, size_t ws_size,
                              hipStream_t stream) {
  const float* we      = (const float*)d_in[0];
  const float* be      = (const float*)d_in[1];
  const int*   seq_len = (const int*)d_in[2];
  const int*   lex_num = (const int*)d_in[3];
  const int*   pos_s   = (const int*)d_in[4];
  const int*   pos_e   = (const int*)d_in[5];
  const float* pe      = (const float*)d_in[6];
  const float* Wf1     = (const float*)d_in[7];
  const float* bf1     = (const float*)d_in[8];
  const float* Wf2     = (const float*)d_in[9];
  const float* bf2     = (const float*)d_in[10];
  const float* Wq = (const float*)d_in[11]; const float* bq = (const float*)d_in[12];
  const float* Wk = (const float*)d_in[13]; const float* bk = (const float*)d_in[14];
  const float* Wv = (const float*)d_in[15]; const float* bv = (const float*)d_in[16];
  const float* Wr = (const float*)d_in[17]; const float* br = (const float*)d_in[18];
  const float* uu = (const float*)d_in[19]; const float* vv = (const float*)d_in[20];
  const float* Wo = (const float*)d_in[21]; const float* bo = (const float*)d_in[22];
  const float* g1 = (const float*)d_in[23]; const float* be1 = (const float*)d_in[24];
  const float* W1 = (const float*)d_in[25]; const float* b1 = (const float*)d_in[26];
  const float* W2 = (const float*)d_in[27]; const float* b2 = (const float*)d_in[28];
  const float* g2 = (const float*)d_in[29]; const float* be2 = (const float*)d_in[30];

  // workspace layout (all 16B-aligned)
  char* ws = (char*)d_ws;
  float* x    = (float*)(ws + 0);          // [384,768]
  float* qb   = (float*)(ws + 1179648);    // [384,768]
  float* kb   = (float*)(ws + 2359296);    // [384,768]
  float* vbuf = (float*)(ws + 3538944);    // [384,768]
  float* PRb  = (float*)(ws + 4718592);    // [383,768]  = pe_used @ Wr + br
  bf16*  Tt   = (bf16*) (ws + 5898240);    // [4,384,3072] bf16
  float* G    = (float*)(ws + 15335424);   // [2,8,192,384]
  float* att  = (float*)(ws + 20054016);   // [2,8,192,192]
  float* ctx  = (float*)(ws + 22413312);   // [384,768]
  float* ao   = (float*)(ws + 23592960);   // [384,768]
  float* x1   = (float*)(ws + 24772608);   // [384,768]
  float* ff   = (float*)(ws + 25952256);   // [384,768]
  float* fo   = (float*)(ws + 27131904);   // [384,768]
  float* out  = (float*)d_out;

  const float* peu = pe + (size_t)JOFF * HH;   // used pe rows [321..703]

  // x = word + bert
  add_kernel<<<288, 256, 0, stream>>>((const float4*)we, (const float4*)be, (float4*)x, 73728);
  // PRb = peu @ Wr + br
  gemm_f32<false, false><<<dim3(12, 6), 256, 0, stream>>>(peu, Wr, br, PRb, NJ, HH, HH);
  // T_f = peu @ Wf1[f*H:(f+1)*H, :]   (bf16 tables)
  for (int f = 0; f < 4; ++f)
    gemm_f32<true, false><<<dim3(48, 6), 256, 0, stream>>>(peu, Wf1 + (size_t)f * HH * H4,
        nullptr, Tt + (size_t)f * NJP * H4, NJ, H4, HH);
  // q,k,v projections
  gemm_f32<false, false><<<dim3(12, 6), 256, 0, stream>>>(x, Wq, bq, qb, BB * SS, HH, HH);
  gemm_f32<false, false><<<dim3(12, 6), 256, 0, stream>>>(x, Wk, bk, kb, BB * SS, HH, HH);
  gemm_f32<false, false><<<dim3(12, 6), 256, 0, stream>>>(x, Wv, bv, vbuf, BB * SS, HH, HH);
  // G precompute
  g_kernel<<<BB * NHH * SS, 128, 0, stream>>>(qb, PRb, vv, G);
  // pair kernel -> att holds BD
  pair_kernel<<<1152, 256, 0, stream>>>(Tt, bf1, Wf2, bf2, pos_s, pos_e, G, att);
  // AC + BD, mask, softmax -> att holds pattn
  attn_kernel<<<BB * NHH * SS, 256, 0, stream>>>(qb, kb, uu, seq_len, lex_num, att);
  // ctx = pattn @ v
  ctx_kernel<<<BB * SS, 256, 0, stream>>>(att, vbuf, ctx);
  // out-proj, LN1, FFN, LN2
  gemm_f32<false, false><<<dim3(12, 6), 256, 0, stream>>>(ctx, Wo, bo, ao, BB * SS, HH, HH);
  ln_kernel<<<BB * SS, 256, 0, stream>>>(x, ao, g1, be1, x1);
  gemm_f32<false, true><<<dim3(12, 6), 256, 0, stream>>>(x1, W1, b1, ff, BB * SS, HH, HH);
  gemm_f32<false, false><<<dim3(12, 6), 256, 0, stream>>>(ff, W2, b2, fo, BB * SS, HH, HH);
  ln_kernel<<<BB * SS, 256, 0, stream>>>(x1, fo, g2, be2, out);
}

// Round 3
// 869.030 us; speedup vs baseline: 1.1445x; 1.1445x over previous
//
#include <hip/hip_runtime.h>
#include <hip/hip_bf16.h>
#include <hip/hip_fp16.h>
#include <cstdint>

#define BB 2
#define SS 192
#define HH 768
#define NHH 8
#define DHH 96
#define H4 3072
#define NJ 383          // used pe rows: idx in [321, 703]
#define NJP 384
#define JOFF 321
#define ATT_SCALE 0.10206207261596575f   // 1/sqrt(96)

typedef _Float16 h2 __attribute__((ext_vector_type(2)));
typedef _Float16 h4v __attribute__((ext_vector_type(4)));
typedef _Float16 h8 __attribute__((ext_vector_type(8)));
typedef float f4 __attribute__((ext_vector_type(4)));

// ---------------- x = a + b (elementwise, float4) ----------------
__global__ __launch_bounds__(256) void add_kernel(const float4* __restrict__ a,
    const float4* __restrict__ b, float4* __restrict__ o, int n4) {
  int i = blockIdx.x * 256 + threadIdx.x;
  if (i < n4) {
    float4 va = a[i], vb = b[i];
    o[i] = make_float4(va.x + vb.x, va.y + vb.y, va.z + vb.z, va.w + vb.w);
  }
}

// ---------------- transpose + f32->f16: dst[n][k] = src[k][n] ----------------
// grid (N/32, K/32, batch); src += z*K*N, dst += z*K*N
__global__ __launch_bounds__(256) void trans_cvt(const float* __restrict__ src,
    __half* __restrict__ dst, int K, int N) {
  __shared__ float tile[32][33];
  const size_t zoff = (size_t)blockIdx.z * K * N;
  src += zoff; dst += zoff;
  const int x = blockIdx.x * 32, y = blockIdx.y * 32;
  const int tx = threadIdx.x & 31, ty = threadIdx.x >> 5;   // ty 0..7
#pragma unroll
  for (int i = 0; i < 4; ++i)
    tile[ty + 8 * i][tx] = src[(size_t)(y + ty + 8 * i) * N + x + tx];
  __syncthreads();
#pragma unroll
  for (int i = 0; i < 4; ++i)
    dst[(size_t)(x + ty + 8 * i) * K + y + tx] = __float2half(tile[tx][ty + 8 * i]);
}

// ---------------- MFMA GEMM: C[M,N] = A[M,K](f32) @ BT[N,K](f16)^T ----------------
// 128x128 tile, 4 waves (2x2 of 64x64), 16x16x32 f16 MFMA, f32 accum.
// Requires N%128==0, K%32==0. M guarded. batch z: BT += z*sB, C += z*sC (elements).
template<bool OUT_HALF, bool RELU>
__global__ __launch_bounds__(256) void mfma_gemm(const float* __restrict__ A,
    const __half* __restrict__ BT, const float* __restrict__ bias, void* __restrict__ Cv,
    int M, int N, int K, long sB, long sC) {
  __shared__ _Float16 As[128][40];
  __shared__ _Float16 Bs[128][40];
  const int t = threadIdx.x;
  const int z = blockIdx.z;
  const __half* Bb = BT + (size_t)z * sB;
  const int bm = blockIdx.y * 128, bn = blockIdx.x * 128;
  const int wave = t >> 6, lane = t & 63;
  const int wr = (wave >> 1) * 64, wc = (wave & 1) * 64;
  const int lrow = lane & 15, khalf = lane >> 4;   // khalf 0..3
  f4 acc[4][4] = {};
  for (int kt = 0; kt < K; kt += 32) {
    __syncthreads();
    // stage A: 1024 chunks (row=j>>3, c=j&7), float4 -> 4 f16
#pragma unroll
    for (int i = 0; i < 4; ++i) {
      const int j = t + (i << 8);
      const int row = j >> 3, c = j & 7;
      float4 av = make_float4(0.f, 0.f, 0.f, 0.f);
      if (bm + row < M) av = *(const float4*)(A + (size_t)(bm + row) * K + kt + (c << 2));
      h4v hv = {(_Float16)av.x, (_Float16)av.y, (_Float16)av.z, (_Float16)av.w};
      *(h4v*)&As[row][c << 2] = hv;
    }
    // stage B: 512 chunks (n=j>>2, c=j&3), 16B f16
#pragma unroll
    for (int i = 0; i < 2; ++i) {
      const int j = t + (i << 8);
      const int n = j >> 2, c = j & 3;
      h8 bv = *(const h8*)(Bb + (size_t)(bn + n) * K + kt + (c << 3));
      *(h8*)&Bs[n][c << 3] = bv;
    }
    __syncthreads();
    h8 af[4], bf[4];
#pragma unroll
    for (int mi = 0; mi < 4; ++mi) af[mi] = *(const h8*)&As[wr + mi * 16 + lrow][khalf << 3];
#pragma unroll
    for (int ni = 0; ni < 4; ++ni) bf[ni] = *(const h8*)&Bs[wc + ni * 16 + lrow][khalf << 3];
#pragma unroll
    for (int mi = 0; mi < 4; ++mi)
#pragma unroll
      for (int ni = 0; ni < 4; ++ni)
        acc[mi][ni] = __builtin_amdgcn_mfma_f32_16x16x32_f16(af[mi], bf[ni], acc[mi][ni], 0, 0, 0);
  }
  const int crow0 = (lane >> 4) << 2;
  const int ccol = lane & 15;
#pragma unroll
  for (int mi = 0; mi < 4; ++mi) {
#pragma unroll
    for (int r = 0; r < 4; ++r) {
      const int row = bm + wr + mi * 16 + crow0 + r;
      if (row >= M) continue;
#pragma unroll
      for (int ni = 0; ni < 4; ++ni) {
        const int col = bn + wc + ni * 16 + ccol;
        float v = acc[mi][ni][r];
        if (bias) v += bias[col];
        if (RELU) v = fmaxf(v, 0.f);
        if (OUT_HALF) ((__half*)Cv)[(size_t)z * sC + (size_t)row * N + col] = __float2half(v);
        else          ((float*)Cv)[(size_t)z * sC + (size_t)row * N + col] = v;
      }
    }
  }
}

// ---------------- pack wf2/bf1 into half2 form for pair_kernel ----------------
__global__ __launch_bounds__(256) void pack_kernel(const float* __restrict__ wf2,
    const float* __restrict__ bf1, h2* __restrict__ wf2pG, h2* __restrict__ bf1pG) {
  for (int i = threadIdx.x; i < 6144; i += 256) {
    const int cw = i >> 2, f = i & 3;
    h2 v = {(_Float16)wf2[8 * cw + f], (_Float16)wf2[8 * cw + 4 + f]};
    wf2pG[i] = v;
  }
  for (int i = threadIdx.x; i < 1536; i += 256) {
    h2 v = {(_Float16)bf1[2 * i], (_Float16)bf1[2 * i + 1]};
    bf1pG[i] = v;
  }
}

// ---------------- G[b,n,q,j] = dot(q[b,q,n,:]+v[n,:], PRb[j,n,:]) ----------------
__global__ __launch_bounds__(128) void g_kernel(const float* __restrict__ qb,
    const float* __restrict__ PRb, const float* __restrict__ vbias, float* __restrict__ G) {
  const int idx = blockIdx.x;                   // (b*8+n)*192 + q
  const int qq = idx % SS; const int bn = idx / SS;
  const int n = bn & 7; const int b = bn >> 3;
  __shared__ float qu[DHH];
  const int t = threadIdx.x;
  if (t < DHH) qu[t] = qb[(size_t)(b * SS + qq) * HH + n * DHH + t] + vbias[n * DHH + t];
  __syncthreads();
  for (int j = t; j < NJ; j += 128) {
    const float* pr = PRb + (size_t)j * HH + n * DHH;
    float s = 0.f;
#pragma unroll
    for (int d = 0; d < DHH; d += 4) {
      const float4 pv = *(const float4*)(pr + d);
      const float4 qv = *(const float4*)(qu + d);
      s += qv.x * pv.x + qv.y * pv.y + qv.z * pv.z + qv.w * pv.w;
    }
    G[(size_t)idx * NJP + j] = s;
  }
}

// ---------------- per-(b,q,k) pair kernel: w4 softmax + BD scores ----------------
__global__ __launch_bounds__(256) void pair_kernel(const h2* __restrict__ Tt,
    const h8* __restrict__ wf2pG, const h2* __restrict__ bf1pG,
    const int* __restrict__ pos_s, const int* __restrict__ pos_e,
    const float* __restrict__ G, float* __restrict__ att) {
  __shared__ h8 wf2p[1536];    // [cw] -> 4 half2 (f=0..3)
  __shared__ h2 bf1p[1536];
  for (int i = threadIdx.x; i < 1536; i += 256) { wf2p[i] = wf2pG[i]; bf1p[i] = bf1pG[i]; }
  __syncthreads();
  const int wave = threadIdx.x >> 6, lane = threadIdx.x & 63;
  const int pbase = blockIdx.x * 64 + wave * 16;
  const h2 zero2 = {(_Float16)0.f, (_Float16)0.f};
  for (int it = 0; it < 16; ++it) {
    const int p = pbase + it;
    const int b = p / (SS * SS);
    const int rem = p - b * (SS * SS);
    const int qq = rem / SS;
    const int kk = rem - qq * SS;
    const int psq = pos_s[b * SS + qq], peq = pos_e[b * SS + qq];
    const int psk = pos_s[b * SS + kk], pek = pos_e[b * SS + kk];
    const int j0 = min(max(psq - psk + 512 - JOFF, 0), NJ - 1);
    const int j1 = min(max(psq - pek + 512 - JOFF, 0), NJ - 1);
    const int j2 = min(max(peq - psk + 512 - JOFF, 0), NJ - 1);
    const int j3 = min(max(peq - pek + 512 - JOFF, 0), NJ - 1);
    const h2* t0 = Tt + (size_t)j0 * 1536;
    const h2* t1 = Tt + (size_t)(NJP + j1) * 1536;
    const h2* t2 = Tt + (size_t)(2 * NJP + j2) * 1536;
    const h2* t3 = Tt + (size_t)(3 * NJP + j3) * 1536;
    h2 acc0 = zero2, acc1 = zero2, acc2 = zero2, acc3 = zero2;
#pragma unroll 6
    for (int m = 0; m < 24; ++m) {
      const int cw = lane + (m << 6);
      h2 s = t0[cw] + t1[cw];
      s = s + t2[cw];
      s = s + t3[cw];
      s = s + bf1p[cw];
      s = __builtin_elementwise_max(s, zero2);
      union { h8 v; h2 p[4]; } W;
      W.v = wf2p[cw];
      acc0 += s * W.p[0];
      acc1 += s * W.p[1];
      acc2 += s * W.p[2];
      acc3 += s * W.p[3];
    }
    float a0 = (float)acc0.x + (float)acc0.y;
    float a1 = (float)acc1.x + (float)acc1.y;
    float a2 = (float)acc2.x + (float)acc2.y;
    float a3 = (float)acc3.x + (float)acc3.y;
#pragma unroll
    for (int off = 32; off > 0; off >>= 1) {
      a0 += __shfl_xor(a0, off, 64);
      a1 += __shfl_xor(a1, off, 64);
      a2 += __shfl_xor(a2, off, 64);
      a3 += __shfl_xor(a3, off, 64);
    }
    const float mx = fmaxf(fmaxf(a0, a1), fmaxf(a2, a3));
    const float e0 = __expf(a0 - mx), e1 = __expf(a1 - mx);
    const float e2 = __expf(a2 - mx), e3 = __expf(a3 - mx);
    const float inv = 1.f / (e0 + e1 + e2 + e3);
    const int n = (lane >> 2) & 7, f = lane & 3;
    const int jf = (f == 0) ? j0 : (f == 1) ? j1 : (f == 2) ? j2 : j3;
    const float wsel = ((f == 0) ? e0 : (f == 1) ? e1 : (f == 2) ? e2 : e3) * inv;
    float g = wsel * G[(size_t)((b * NHH + n) * SS + qq) * NJP + jf];
    g += __shfl_xor(g, 1, 64);
    g += __shfl_xor(g, 2, 64);
    if (lane < 32 && (lane & 3) == 0)
      att[(size_t)((b * NHH + n) * SS + qq) * SS + kk] = g;
  }
}

// ---------------- attention: att = softmax_k((AC+BD)*scale + mask) ----------------
__global__ __launch_bounds__(256) void attn_kernel(const float* __restrict__ qb,
    const float* __restrict__ kb, const float* __restrict__ u,
    const int* __restrict__ seq_len, const int* __restrict__ lex_num,
    float* __restrict__ att) {
  const int idx = blockIdx.x;                  // (b*8+n)*192 + q
  const int qq = idx % SS; const int bn = idx / SS;
  const int n = bn & 7; const int b = bn >> 3;
  __shared__ float qu[DHH];
  __shared__ float red[256];
  const int t = threadIdx.x;
  if (t < DHH) qu[t] = qb[(size_t)(b * SS + qq) * HH + n * DHH + t] + u[n * DHH + t];
  __syncthreads();
  const int vbnd = seq_len[b] + lex_num[b];
  float val = -3.0e38f;
  if (t < SS) {
    const float* kr = kb + (size_t)(b * SS + t) * HH + n * DHH;
    float ac = 0.f;
#pragma unroll
    for (int d = 0; d < DHH; d += 4) {
      const float4 kv = *(const float4*)(kr + d);
      const float4 qv = *(const float4*)(qu + d);
      ac += qv.x * kv.x + qv.y * kv.y + qv.z * kv.z + qv.w * kv.w;
    }
    val = (ac + att[(size_t)idx * SS + t]) * ATT_SCALE;
    if (t >= vbnd) val = -1e15f;
  }
  red[t] = val; __syncthreads();
  for (int s = 128; s > 0; s >>= 1) { if (t < s) red[t] = fmaxf(red[t], red[t + s]); __syncthreads(); }
  const float mx = red[0]; __syncthreads();
  const float e = (t < SS) ? __expf(val - mx) : 0.f;
  red[t] = e; __syncthreads();
  for (int s = 128; s > 0; s >>= 1) { if (t < s) red[t] += red[t + s]; __syncthreads(); }
  const float inv = 1.f / red[0];
  if (t < SS) att[(size_t)idx * SS + t] = e * inv;
}

// ---------------- ctx[b,q,:] = sum_k pattn[b,n,q,k] * v[b,k,n,:] ----------------
__global__ __launch_bounds__(256) void ctx_kernel(const float* __restrict__ att,
    const float* __restrict__ vb, float* __restrict__ ctx) {
  const int idx = blockIdx.x;                  // b*192 + q
  const int qq = idx % SS, b = idx / SS;
  __shared__ float ps[NHH * SS];
  const int t = threadIdx.x;
  for (int i = t; i < NHH * SS; i += 256) {
    const int n = i / SS, k = i - n * SS;
    ps[i] = att[(size_t)((b * NHH + n) * SS + qq) * SS + k];
  }
  __syncthreads();
#pragma unroll
  for (int rep = 0; rep < 3; ++rep) {
    const int o = t + rep * 256;
    const int n = o / DHH;
    const float* vp = vb + (size_t)b * SS * HH + o;
    const float* pp = ps + n * SS;
    float acc = 0.f;
#pragma unroll 4
    for (int k = 0; k < SS; ++k) acc += pp[k] * vp[(size_t)k * HH];
    ctx[(size_t)idx * HH + o] = acc;
  }
}

// ---------------- out = LayerNorm(xin + dres) * g + b ----------------
__global__ __launch_bounds__(256) void ln_kernel(const float* __restrict__ xin,
    const float* __restrict__ dres, const float* __restrict__ g,
    const float* __restrict__ bta, float* __restrict__ out) {
  const int row = blockIdx.x;
  const int t = threadIdx.x;
  __shared__ float red[256];
  const size_t base = (size_t)row * HH;
  const float v0 = xin[base + t] + dres[base + t];
  const float v1 = xin[base + 256 + t] + dres[base + 256 + t];
  const float v2 = xin[base + 512 + t] + dres[base + 512 + t];
  red[t] = v0 + v1 + v2; __syncthreads();
  for (int s = 128; s > 0; s >>= 1) { if (t < s) red[t] += red[t + s]; __syncthreads(); }
  const float mean = red[0] * (1.f / 768.f); __syncthreads();
  red[t] = v0 * v0 + v1 * v1 + v2 * v2; __syncthreads();
  for (int s = 128; s > 0; s >>= 1) { if (t < s) red[t] += red[t + s]; __syncthreads(); }
  const float var = red[0] * (1.f / 768.f) - mean * mean;
  const float rstd = rsqrtf(var + 1e-5f);
  out[base + t]       = (v0 - mean) * rstd * g[t]       + bta[t];
  out[base + 256 + t] = (v1 - mean) * rstd * g[256 + t] + bta[256 + t];
  out[base + 512 + t] = (v2 - mean) * rstd * g[512 + t] + bta[512 + t];
}

extern "C" void kernel_launch(void* const* d_in, const int* in_sizes, int n_in,
                              void* d_out, int out_size, void* d_ws, size_t ws_size,
                              hipStream_t stream) {
  const float* we      = (const float*)d_in[0];
  const float* be      = (const float*)d_in[1];
  const int*   seq_len = (const int*)d_in[2];
  const int*   lex_num = (const int*)d_in[3];
  const int*   pos_s   = (const int*)d_in[4];
  const int*   pos_e   = (const int*)d_in[5];
  const float* pe      = (const float*)d_in[6];
  const float* Wf1     = (const float*)d_in[7];
  const float* bf1     = (const float*)d_in[8];
  const float* Wf2     = (const float*)d_in[9];
  const float* bf2     = (const float*)d_in[10];
  const float* Wq = (const float*)d_in[11]; const float* bq = (const float*)d_in[12];
  const float* Wk = (const float*)d_in[13]; const float* bk = (const float*)d_in[14];
  const float* Wv = (const float*)d_in[15]; const float* bv = (const float*)d_in[16];
  const float* Wr = (const float*)d_in[17]; const float* br = (const float*)d_in[18];
  const float* uu = (const float*)d_in[19]; const float* vv = (const float*)d_in[20];
  const float* Wo = (const float*)d_in[21]; const float* bo = (const float*)d_in[22];
  const float* g1 = (const float*)d_in[23]; const float* be1 = (const float*)d_in[24];
  const float* W1 = (const float*)d_in[25]; const float* b1 = (const float*)d_in[26];
  const float* W2 = (const float*)d_in[27]; const float* b2 = (const float*)d_in[28];
  const float* g2 = (const float*)d_in[29]; const float* be2 = (const float*)d_in[30];

  // workspace layout (bytes, all 16B aligned)
  char* ws = (char*)d_ws;
  float*  x     = (float*)(ws + 0);          // [384,768]
  float*  qb    = (float*)(ws + 1179648);    // [384,768]; ctx aliases after attn
  float*  kb    = (float*)(ws + 2359296);    // [384,768]; x1 aliases after attn
  float*  vbuf  = (float*)(ws + 3538944);    // [384,768]
  float*  PRb   = (float*)(ws + 4718592);    // [383,768]
  __half* Tt    = (__half*)(ws + 5898240);   // [4,384,3072] f16
  __half* BTf1  = (__half*)(ws + 15335424);  // [4,3072,768] f16 (dead after T-gemm)
  float*  G     = (float*)(ws + 15335424);   // [2,8,192,384] (aliases BTf1)
  float*  att   = (float*)(ws + 20054016);   // [2,8,192,192] (aliases BTf1)
  float*  ff    = (float*)(ws + 22413312);   // [384,768]     (aliases BTf1)
  float*  fo    = (float*)(ws + 23592960);   // [384,768]     (aliases BTf1)
  float*  ao    = (float*)(ws + 24772608);   // [384,768]     (aliases BTf1)
  __half* BTsq  = (__half*)(ws + 34209792);  // [7,768,768] f16: Wr,Wq,Wk,Wv,Wo,W1,W2
  h2*     wf2pG = (h2*)(ws + 42467328);      // [1536*4]
  h2*     bf1pG = (h2*)(ws + 42491904);      // [1536]
  float*  ctx   = qb;
  float*  x1    = kb;
  float*  out   = (float*)d_out;

  const float* peu = pe + (size_t)JOFF * HH;
  const size_t SQ = (size_t)HH * HH;         // 589824
  __half* WrT = BTsq + 0 * SQ; __half* WqT = BTsq + 1 * SQ; __half* WkT = BTsq + 2 * SQ;
  __half* WvT = BTsq + 3 * SQ; __half* WoT = BTsq + 4 * SQ; __half* W1T = BTsq + 5 * SQ;
  __half* W2T = BTsq + 6 * SQ;

  // x = word + bert
  add_kernel<<<288, 256, 0, stream>>>((const float4*)we, (const float4*)be, (float4*)x, 73728);
  // pack wf2/bf1
  pack_kernel<<<1, 256, 0, stream>>>(Wf2, bf1, wf2pG, bf1pG);
  // transposes: Wf1 (4 slices of [768,3072] -> [3072,768]), 7 square weights
  trans_cvt<<<dim3(96, 24, 4), 256, 0, stream>>>(Wf1, BTf1, HH, H4);
  trans_cvt<<<dim3(24, 24, 1), 256, 0, stream>>>(Wr, WrT, HH, HH);
  trans_cvt<<<dim3(24, 24, 1), 256, 0, stream>>>(Wq, WqT, HH, HH);
  trans_cvt<<<dim3(24, 24, 1), 256, 0, stream>>>(Wk, WkT, HH, HH);
  trans_cvt<<<dim3(24, 24, 1), 256, 0, stream>>>(Wv, WvT, HH, HH);
  trans_cvt<<<dim3(24, 24, 1), 256, 0, stream>>>(Wo, WoT, HH, HH);
  trans_cvt<<<dim3(24, 24, 1), 256, 0, stream>>>(W1, W1T, HH, HH);
  trans_cvt<<<dim3(24, 24, 1), 256, 0, stream>>>(W2, W2T, HH, HH);
  // PRb = peu @ Wr + br   (f32 out)
  mfma_gemm<false, false><<<dim3(6, 3, 1), 256, 0, stream>>>(peu, WrT, br, PRb, NJ, HH, HH, 0, 0);
  // T_f = peu @ Wf1_f     (f16 out, batched over f)
  mfma_gemm<true, false><<<dim3(24, 3, 4), 256, 0, stream>>>(peu, BTf1, nullptr, Tt,
      NJ, H4, HH, (long)H4 * HH, (long)NJP * H4);
  // q,k,v projections
  mfma_gemm<false, false><<<dim3(6, 3, 1), 256, 0, stream>>>(x, WqT, bq, qb, BB * SS, HH, HH, 0, 0);
  mfma_gemm<false, false><<<dim3(6, 3, 1), 256, 0, stream>>>(x, WkT, bk, kb, BB * SS, HH, HH, 0, 0);
  mfma_gemm<false, false><<<dim3(6, 3, 1), 256, 0, stream>>>(x, WvT, bv, vbuf, BB * SS, HH, HH, 0, 0);
  // G precompute
  g_kernel<<<BB * NHH * SS, 128, 0, stream>>>(qb, PRb, vv, G);
  // pair kernel -> att holds BD
  pair_kernel<<<1152, 256, 0, stream>>>((const h2*)Tt, (const h8*)wf2pG, bf1pG,
      pos_s, pos_e, G, att);
  // AC + BD, mask, softmax -> att holds pattn
  attn_kernel<<<BB * NHH * SS, 256, 0, stream>>>(qb, kb, uu, seq_len, lex_num, att);
  // ctx = pattn @ v   (ctx aliases qb; qb dead after attn_kernel)
  ctx_kernel<<<BB * SS, 256, 0, stream>>>(att, vbuf, ctx);
  // out-proj, LN1, FFN, LN2
  mfma_gemm<false, false><<<dim3(6, 3, 1), 256, 0, stream>>>(ctx, WoT, bo, ao, BB * SS, HH, HH, 0, 0);
  ln_kernel<<<BB * SS, 256, 0, stream>>>(x, ao, g1, be1, x1);
  mfma_gemm<false, true><<<dim3(6, 3, 1), 256, 0, stream>>>(x1, W1T, b1, ff, BB * SS, HH, HH, 0, 0);
  mfma_gemm<false, false><<<dim3(6, 3, 1), 256, 0, stream>>>(ff, W2T, b2, fo, BB * SS, HH, HH, 0, 0);
  ln_kernel<<<BB * SS, 256, 0, stream>>>(x1, fo, g2, be2, out);
}

// Round 5
// 537.321 us; speedup vs baseline: 1.8510x; 1.6173x over previous
//
#include <hip/hip_runtime.h>
#include <hip/hip_bf16.h>
#include <hip/hip_fp16.h>
#include <cstdint>

#define BB 2
#define SS 192
#define HH 768
#define NHH 8
#define DHH 96
#define H4 3072
#define NJ 383          // used pe rows: idx in [321, 703]
#define NJP 384
#define JOFF 321
#define NPAIR 73728     // 2*192*192
#define ATT_SCALE 0.10206207261596575f   // 1/sqrt(96)

typedef _Float16 h2 __attribute__((ext_vector_type(2)));
typedef _Float16 h4v __attribute__((ext_vector_type(4)));
typedef _Float16 h8 __attribute__((ext_vector_type(8)));
typedef float f4 __attribute__((ext_vector_type(4)));

// ---------------- x = a + b ----------------
__global__ __launch_bounds__(256) void add_kernel(const float4* __restrict__ a,
    const float4* __restrict__ b, float4* __restrict__ o, int n4) {
  int i = blockIdx.x * 256 + threadIdx.x;
  if (i < n4) {
    float4 va = a[i], vb = b[i];
    o[i] = make_float4(va.x + vb.x, va.y + vb.y, va.z + vb.z, va.w + vb.w);
  }
}

// ---------------- transpose + f32->f16 (for Wf1): dst[n][k] = src[k][n] ----------------
__global__ __launch_bounds__(256) void trans_cvt(const float* __restrict__ src,
    __half* __restrict__ dst, int K, int N) {
  __shared__ float tile[32][33];
  const size_t zoff = (size_t)blockIdx.z * K * N;
  src += zoff; dst += zoff;
  const int x = blockIdx.x * 32, y = blockIdx.y * 32;
  const int tx = threadIdx.x & 31, ty = threadIdx.x >> 5;
#pragma unroll
  for (int i = 0; i < 4; ++i)
    tile[ty + 8 * i][tx] = src[(size_t)(y + ty + 8 * i) * N + x + tx];
  __syncthreads();
#pragma unroll
  for (int i = 0; i < 4; ++i)
    dst[(size_t)(x + ty + 8 * i) * K + y + tx] = __float2half(tile[tx][ty + 8 * i]);
}

// ---------------- 7 square-weight transposes in one launch ----------------
__global__ __launch_bounds__(256) void trans7(const float* __restrict__ s0,
    const float* __restrict__ s1, const float* __restrict__ s2, const float* __restrict__ s3,
    const float* __restrict__ s4, const float* __restrict__ s5, const float* __restrict__ s6,
    __half* __restrict__ dstBase) {
  __shared__ float tile[32][33];
  const int z = blockIdx.z;
  const float* src;
  switch (z) {
    case 0: src = s0; break; case 1: src = s1; break; case 2: src = s2; break;
    case 3: src = s3; break; case 4: src = s4; break; case 5: src = s5; break;
    default: src = s6; break;
  }
  __half* dst = dstBase + (size_t)z * HH * HH;
  const int x = blockIdx.x * 32, y = blockIdx.y * 32;
  const int tx = threadIdx.x & 31, ty = threadIdx.x >> 5;
#pragma unroll
  for (int i = 0; i < 4; ++i)
    tile[ty + 8 * i][tx] = src[(size_t)(y + ty + 8 * i) * HH + x + tx];
  __syncthreads();
#pragma unroll
  for (int i = 0; i < 4; ++i)
    dst[(size_t)(x + ty + 8 * i) * HH + y + tx] = __float2half(tile[tx][ty + 8 * i]);
}

// ---------------- MFMA GEMM: C[M,N] = A[M,K](f32) @ BT[N,K](f16)^T, BK=64 pipelined ----
template<bool OUT_HALF, bool RELU>
__global__ __launch_bounds__(256) void mfma_gemm(const float* __restrict__ A,
    const __half* __restrict__ BT, const float* __restrict__ bias, void* __restrict__ Cv,
    int M, int N, int K, long sB, long sC) {
  __shared__ _Float16 As[128][72];
  __shared__ _Float16 Bs[128][72];
  const int t = threadIdx.x;
  const int z = blockIdx.z;
  const __half* Bb = BT + (size_t)z * sB;
  const int bm = blockIdx.y * 128, bn = blockIdx.x * 128;
  const int wave = t >> 6, lane = t & 63;
  const int wr = (wave >> 1) * 64, wc = (wave & 1) * 64;
  const int lrow = lane & 15, khalf = lane >> 4;
  const int arow = t >> 4, acol = (t & 15) << 2;   // A: rows arow+16i, cols [acol,acol+4)
  const int brow = t >> 3, bcol = (t & 7) << 3;    // B: rows brow+32i, cols [bcol,bcol+8)
  f4 acc[4][4] = {};
  const int nk = K >> 6;
  float4 ra[8]; h8 rb[4];

#define LOAD_TILE(kt) { \
  _Pragma("unroll") for (int i = 0; i < 8; ++i) { \
    const int row = arow + (i << 4); \
    if (bm + row < M) ra[i] = *(const float4*)(A + (size_t)(bm + row) * K + (size_t)(kt) * 64 + acol); \
    else ra[i] = make_float4(0.f, 0.f, 0.f, 0.f); } \
  _Pragma("unroll") for (int i = 0; i < 4; ++i) { \
    const int row = brow + (i << 5); \
    rb[i] = *(const h8*)(Bb + (size_t)(bn + row) * K + (size_t)(kt) * 64 + bcol); } }

#define STORE_TILE() { \
  _Pragma("unroll") for (int i = 0; i < 8; ++i) { \
    const int row = arow + (i << 4); \
    h4v hv = {(_Float16)ra[i].x, (_Float16)ra[i].y, (_Float16)ra[i].z, (_Float16)ra[i].w}; \
    *(h4v*)&As[row][acol] = hv; } \
  _Pragma("unroll") for (int i = 0; i < 4; ++i) { \
    const int row = brow + (i << 5); \
    *(h8*)&Bs[row][bcol] = rb[i]; } }

  LOAD_TILE(0)
  STORE_TILE()
  __syncthreads();
  for (int kt = 0; kt < nk; ++kt) {
    const bool more = (kt + 1 < nk);
    if (more) { LOAD_TILE(kt + 1) }
#pragma unroll
    for (int ks = 0; ks < 2; ++ks) {
      h8 af[4], bf[4];
#pragma unroll
      for (int mi = 0; mi < 4; ++mi) af[mi] = *(const h8*)&As[wr + mi * 16 + lrow][ks * 32 + (khalf << 3)];
#pragma unroll
      for (int ni = 0; ni < 4; ++ni) bf[ni] = *(const h8*)&Bs[wc + ni * 16 + lrow][ks * 32 + (khalf << 3)];
#pragma unroll
      for (int mi = 0; mi < 4; ++mi)
#pragma unroll
        for (int ni = 0; ni < 4; ++ni)
          acc[mi][ni] = __builtin_amdgcn_mfma_f32_16x16x32_f16(af[mi], bf[ni], acc[mi][ni], 0, 0, 0);
    }
    __syncthreads();
    if (more) { STORE_TILE() }
    __syncthreads();
  }
#undef LOAD_TILE
#undef STORE_TILE
  const int crow0 = (lane >> 4) << 2;
  const int ccol = lane & 15;
#pragma unroll
  for (int mi = 0; mi < 4; ++mi) {
#pragma unroll
    for (int r = 0; r < 4; ++r) {
      const int row = bm + wr + mi * 16 + crow0 + r;
      if (row >= M) continue;
#pragma unroll
      for (int ni = 0; ni < 4; ++ni) {
        const int col = bn + wc + ni * 16 + ccol;
        float v = acc[mi][ni][r];
        if (bias) v += bias[col];
        if (RELU) v = fmaxf(v, 0.f);
        if (OUT_HALF) ((__half*)Cv)[(size_t)z * sC + (size_t)row * N + col] = __float2half(v);
        else          ((float*)Cv)[(size_t)z * sC + (size_t)row * N + col] = v;
      }
    }
  }
}

// ---------------- pack wf2/bf1 (half2) + bqkv concat ----------------
__global__ __launch_bounds__(256) void pack_kernel(const float* __restrict__ wf2,
    const float* __restrict__ bf1, const float* __restrict__ bq, const float* __restrict__ bk,
    const float* __restrict__ bv, h2* __restrict__ wf2pG, h2* __restrict__ bf1pG,
    float* __restrict__ bqkv) {
  for (int i = threadIdx.x; i < 6144; i += 256) {
    const int cw = i >> 2, f = i & 3;
    h2 v = {(_Float16)wf2[8 * cw + f], (_Float16)wf2[8 * cw + 4 + f]};
    wf2pG[i] = v;
  }
  for (int i = threadIdx.x; i < 1536; i += 256) {
    h2 v = {(_Float16)bf1[2 * i], (_Float16)bf1[2 * i + 1]};
    bf1pG[i] = v;
  }
  for (int i = threadIdx.x; i < 768; i += 256) {
    bqkv[i] = bq[i]; bqkv[768 + i] = bk[i]; bqkv[1536 + i] = bv[i];
  }
}

// ---------------- G[b,n,q,j] = dot(q+v, PRb[j,n,:]) — LDS-staged, reg-tiled ----------------
// grid 128: blk = ((b*8+n)*8 + jt), jt covers 48 j
__global__ __launch_bounds__(256) void g2_kernel(const float* __restrict__ qkv,
    const float* __restrict__ PRb, const float* __restrict__ vv, float* __restrict__ G) {
  __shared__ float Qv[192][100];
  __shared__ float PRs[48][100];
  const int blk = blockIdx.x;
  const int jt = blk & 7, n = (blk >> 3) & 7, b = blk >> 6;
  const int j0 = jt * 48;
  const int t = threadIdx.x;
  for (int i = t; i < 4608; i += 256) {
    const int q = i / 24, c = (i % 24) * 4;
    float4 v = *(const float4*)(qkv + (size_t)(b * 192 + q) * 2304 + n * 96 + c);
    const float4 vb = *(const float4*)(vv + n * 96 + c);
    Qv[q][c] = v.x + vb.x; Qv[q][c + 1] = v.y + vb.y;
    Qv[q][c + 2] = v.z + vb.z; Qv[q][c + 3] = v.w + vb.w;
  }
  for (int i = t; i < 1152; i += 256) {
    const int jr = i / 24, c = (i % 24) * 4;
    const int j = min(j0 + jr, NJ - 1);
    *(f4*)&PRs[jr][c] = *(const f4*)(PRb + (size_t)j * 768 + n * 96 + c);
  }
  __syncthreads();
  const int qt = t >> 4, jt2 = t & 15;
  const int qb0 = qt * 12;
  float acc[12][3] = {};
  for (int dq = 0; dq < 24; ++dq) {
    const f4 p0 = *(const f4*)&PRs[jt2][dq * 4];
    const f4 p1 = *(const f4*)&PRs[jt2 + 16][dq * 4];
    const f4 p2 = *(const f4*)&PRs[jt2 + 32][dq * 4];
#pragma unroll
    for (int qi = 0; qi < 12; ++qi) {
      const f4 qv = *(const f4*)&Qv[qb0 + qi][dq * 4];
      acc[qi][0] += qv.x * p0.x + qv.y * p0.y + qv.z * p0.z + qv.w * p0.w;
      acc[qi][1] += qv.x * p1.x + qv.y * p1.y + qv.z * p1.z + qv.w * p1.w;
      acc[qi][2] += qv.x * p2.x + qv.y * p2.y + qv.z * p2.z + qv.w * p2.w;
    }
  }
  float* Grow = G + (size_t)(b * 8 + n) * 192 * NJP;
#pragma unroll
  for (int qi = 0; qi < 12; ++qi)
#pragma unroll
    for (int ji = 0; ji < 3; ++ji)
      Grow[(size_t)(qb0 + qi) * NJP + j0 + jt2 + 16 * ji] = acc[qi][ji];
}

// ---------------- pairA: per-chunk partial w4 logits (XCD-affine channel split) ----------
// grid 4608; chunk = (blk%8)>>1 so each XCD re-reads only a 2.36MB table slice.
__global__ __launch_bounds__(256) void pairA_kernel(const h2* __restrict__ Tt,
    const h8* __restrict__ wf2pG, const h2* __restrict__ bf1pG,
    const int* __restrict__ pos_s, const int* __restrict__ pos_e,
    float* __restrict__ partials) {
  __shared__ h8 wf2s[384];
  __shared__ h2 bf1s[384];
  const int blk = blockIdx.x;
  const int chunk = (blk & 7) >> 1;
  const int cbase = chunk * 384;
  for (int i = threadIdx.x; i < 384; i += 256) { wf2s[i] = wf2pG[cbase + i]; bf1s[i] = bf1pG[cbase + i]; }
  __syncthreads();
  const int wave = threadIdx.x >> 6, lane = threadIdx.x & 63;
  const int pbase = (blk >> 3) * 128 + (blk & 1) * 64 + wave * 16;
  const h2 zero2 = {(_Float16)0.f, (_Float16)0.f};
  for (int it = 0; it < 16; ++it) {
    const int p = pbase + it;
    const int b = p / 36864;
    const int rem = p - b * 36864;
    const int qq = rem / 192;
    const int kk = rem - qq * 192;
    const int psq = pos_s[b * 192 + qq], peq = pos_e[b * 192 + qq];
    const int psk = pos_s[b * 192 + kk], pek = pos_e[b * 192 + kk];
    const int j0 = min(max(psq - psk + 191, 0), NJ - 1);
    const int j1 = min(max(psq - pek + 191, 0), NJ - 1);
    const int j2 = min(max(peq - psk + 191, 0), NJ - 1);
    const int j3 = min(max(peq - pek + 191, 0), NJ - 1);
    const h2* t0 = Tt + (size_t)j0 * 1536 + cbase;
    const h2* t1 = Tt + (size_t)(NJP + j1) * 1536 + cbase;
    const h2* t2 = Tt + (size_t)(2 * NJP + j2) * 1536 + cbase;
    const h2* t3 = Tt + (size_t)(3 * NJP + j3) * 1536 + cbase;
    h2 acc0 = zero2, acc1 = zero2, acc2 = zero2, acc3 = zero2;
#pragma unroll
    for (int m = 0; m < 6; ++m) {
      const int cw = lane + (m << 6);
      h2 s = t0[cw] + t1[cw];
      s = s + t2[cw];
      s = s + t3[cw];
      s = s + bf1s[cw];
      s = __builtin_elementwise_max(s, zero2);
      union { h8 v; h2 pr[4]; } W;
      W.v = wf2s[cw];
      acc0 += s * W.pr[0]; acc1 += s * W.pr[1]; acc2 += s * W.pr[2]; acc3 += s * W.pr[3];
    }
    float a0 = (float)acc0.x + (float)acc0.y;
    float a1 = (float)acc1.x + (float)acc1.y;
    float a2 = (float)acc2.x + (float)acc2.y;
    float a3 = (float)acc3.x + (float)acc3.y;
#pragma unroll
    for (int off = 32; off > 0; off >>= 1) {
      a0 += __shfl_xor(a0, off, 64);
      a1 += __shfl_xor(a1, off, 64);
      a2 += __shfl_xor(a2, off, 64);
      a3 += __shfl_xor(a3, off, 64);
    }
    const float sel = (lane == 0) ? a0 : (lane == 1) ? a1 : (lane == 2) ? a2 : a3;
    if (lane < 4) partials[((size_t)chunk * NPAIR + p) * 4 + lane] = sel;
  }
}

// ---------------- pairB: combine chunk partials -> w4 softmax ----------------
__global__ __launch_bounds__(256) void pairB_kernel(const float4* __restrict__ partials,
    const float* __restrict__ bf2, float4* __restrict__ w4) {
  const int p = blockIdx.x * 256 + threadIdx.x;
  const float4 s0 = partials[p];
  const float4 s1 = partials[NPAIR + p];
  const float4 s2 = partials[2 * NPAIR + p];
  const float4 s3 = partials[3 * NPAIR + p];
  const float a0 = s0.x + s1.x + s2.x + s3.x + bf2[0];
  const float a1 = s0.y + s1.y + s2.y + s3.y + bf2[1];
  const float a2 = s0.z + s1.z + s2.z + s3.z + bf2[2];
  const float a3 = s0.w + s1.w + s2.w + s3.w + bf2[3];
  const float mx = fmaxf(fmaxf(a0, a1), fmaxf(a2, a3));
  const float e0 = __expf(a0 - mx), e1 = __expf(a1 - mx);
  const float e2 = __expf(a2 - mx), e3 = __expf(a3 - mx);
  const float inv = 1.f / (e0 + e1 + e2 + e3);
  w4[p] = make_float4(e0 * inv, e1 * inv, e2 * inv, e3 * inv);
}

// ---------------- attn2: AC (LDS-staged) + BD (w4·G from LDS) + softmax -> pattn f16 ----
// grid 128: blk = ((b*8+n)*8 + qt), 24 q rows per block
__global__ __launch_bounds__(256) void attn2_kernel(const float* __restrict__ qkv,
    const float* __restrict__ uu, const float* __restrict__ G,
    const float4* __restrict__ w4, const int* __restrict__ pos_s, const int* __restrict__ pos_e,
    const int* __restrict__ seq_len, const int* __restrict__ lex_num,
    __half* __restrict__ P) {
  __shared__ float Ks[192][100];
  __shared__ float Qs[24][100];
  __shared__ float Gs[24][388];
  __shared__ int poss[192], pose[192];
  const int blk = blockIdx.x;
  const int qt = blk & 7, n = (blk >> 3) & 7, b = blk >> 6;
  const int q0 = qt * 24;
  const int t = threadIdx.x;
  for (int i = t; i < 4608; i += 256) {
    const int k = i / 24, c = (i % 24) * 4;
    *(f4*)&Ks[k][c] = *(const f4*)(qkv + (size_t)(b * 192 + k) * 2304 + 768 + n * 96 + c);
  }
  for (int i = t; i < 576; i += 256) {
    const int qi = i / 24, c = (i % 24) * 4;
    float4 v = *(const float4*)(qkv + (size_t)(b * 192 + q0 + qi) * 2304 + n * 96 + c);
    const float4 ub = *(const float4*)(uu + n * 96 + c);
    Qs[qi][c] = v.x + ub.x; Qs[qi][c + 1] = v.y + ub.y;
    Qs[qi][c + 2] = v.z + ub.z; Qs[qi][c + 3] = v.w + ub.w;
  }
  for (int i = t; i < 2304; i += 256) {
    const int qi = i / 96, c = (i % 96) * 4;
    *(f4*)&Gs[qi][c] = *(const f4*)(G + ((size_t)(b * 8 + n) * 192 + q0 + qi) * NJP + c);
  }
  for (int i = t; i < 192; i += 256) { poss[i] = pos_s[b * 192 + i]; pose[i] = pos_e[b * 192 + i]; }
  __syncthreads();
  const int wave = t >> 6, lane = t & 63;
  const int qw = wave * 6;
  float ac[6][3] = {};
  for (int dq = 0; dq < 24; ++dq) {
    const f4 kv0 = *(const f4*)&Ks[lane][dq * 4];
    const f4 kv1 = *(const f4*)&Ks[lane + 64][dq * 4];
    const f4 kv2 = *(const f4*)&Ks[lane + 128][dq * 4];
#pragma unroll
    for (int qi = 0; qi < 6; ++qi) {
      const f4 qv = *(const f4*)&Qs[qw + qi][dq * 4];
      ac[qi][0] += qv.x * kv0.x + qv.y * kv0.y + qv.z * kv0.z + qv.w * kv0.w;
      ac[qi][1] += qv.x * kv1.x + qv.y * kv1.y + qv.z * kv1.z + qv.w * kv1.w;
      ac[qi][2] += qv.x * kv2.x + qv.y * kv2.y + qv.z * kv2.z + qv.w * kv2.w;
    }
  }
  const int vbnd = seq_len[b] + lex_num[b];
#pragma unroll
  for (int qi = 0; qi < 6; ++qi) {
    const int qg = q0 + qw + qi;
    const int psq = poss[qg], peq = pose[qg];
    float v[3];
#pragma unroll
    for (int ki = 0; ki < 3; ++ki) {
      const int k = lane + 64 * ki;
      const int psk = poss[k], pek = pose[k];
      const int jss = min(max(psq - psk + 191, 0), NJ - 1);
      const int jse = min(max(psq - pek + 191, 0), NJ - 1);
      const int jes = min(max(peq - psk + 191, 0), NJ - 1);
      const int jee = min(max(peq - pek + 191, 0), NJ - 1);
      const float4 w = w4[(size_t)b * 36864 + (size_t)qg * 192 + k];
      const float bd = w.x * Gs[qw + qi][jss] + w.y * Gs[qw + qi][jse]
                     + w.z * Gs[qw + qi][jes] + w.w * Gs[qw + qi][jee];
      const float a = (ac[qi][ki] + bd) * ATT_SCALE;
      v[ki] = (k < vbnd) ? a : -1e15f;
    }
    float mx = fmaxf(fmaxf(v[0], v[1]), v[2]);
#pragma unroll
    for (int off = 1; off < 64; off <<= 1) mx = fmaxf(mx, __shfl_xor(mx, off, 64));
    const float e0 = __expf(v[0] - mx), e1 = __expf(v[1] - mx), e2 = __expf(v[2] - mx);
    float sm = e0 + e1 + e2;
#pragma unroll
    for (int off = 1; off < 64; off <<= 1) sm += __shfl_xor(sm, off, 64);
    const float inv = 1.f / sm;
    __half* pr = P + ((size_t)(b * 8 + n) * 192 + qg) * 192;
    pr[lane] = __float2half(e0 * inv);
    pr[lane + 64] = __float2half(e1 * inv);
    pr[lane + 128] = __float2half(e2 * inv);
  }
}

// ---------------- ctx2: ctx[b,q,n*96+d] = sum_k P[b,n,q,k] * V[b,k,n*96+d] ----------------
// grid 64: blk = ((b*8+n)*4 + qt), 48 q rows per block
__global__ __launch_bounds__(256) void ctx2_kernel(const __half* __restrict__ P,
    const float* __restrict__ qkv, float* __restrict__ ctx) {
  __shared__ float Vs[192][100];
  __shared__ float Ps[48][196];
  const int blk = blockIdx.x;
  const int qt = blk & 3, n = (blk >> 2) & 7, b = blk >> 5;
  const int q0 = qt * 48;
  const int t = threadIdx.x;
  for (int i = t; i < 4608; i += 256) {
    const int k = i / 24, c = (i % 24) * 4;
    *(f4*)&Vs[k][c] = *(const f4*)(qkv + (size_t)(b * 192 + k) * 2304 + 1536 + n * 96 + c);
  }
  const __half* Pb = P + ((size_t)(b * 8 + n) * 192 + q0) * 192;
  for (int i = t; i < 4608; i += 256) {
    const int qi = i / 96, c = (i % 96) * 2;
    const h2 pv = *(const h2*)(Pb + (size_t)qi * 192 + c);
    Ps[qi][c] = (float)pv.x; Ps[qi][c + 1] = (float)pv.y;
  }
  __syncthreads();
  const int qt2 = t >> 5, dt = t & 31;
  const int qb0 = qt2 * 6;
  float acc[6][3] = {};
  for (int k4 = 0; k4 < 48; ++k4) {
    const int k = k4 * 4;
    f4 pq[6];
#pragma unroll
    for (int qi = 0; qi < 6; ++qi) pq[qi] = *(const f4*)&Ps[qb0 + qi][k];
#pragma unroll
    for (int kk = 0; kk < 4; ++kk) {
      const float v0 = Vs[k + kk][dt];
      const float v1 = Vs[k + kk][dt + 32];
      const float v2 = Vs[k + kk][dt + 64];
#pragma unroll
      for (int qi = 0; qi < 6; ++qi) {
        const float pv = pq[qi][kk];
        acc[qi][0] += pv * v0; acc[qi][1] += pv * v1; acc[qi][2] += pv * v2;
      }
    }
  }
#pragma unroll
  for (int qi = 0; qi < 6; ++qi) {
    float* cr = ctx + (size_t)(b * 192 + q0 + qb0 + qi) * 768 + n * 96;
    cr[dt] = acc[qi][0]; cr[dt + 32] = acc[qi][1]; cr[dt + 64] = acc[qi][2];
  }
}

// ---------------- out = LayerNorm(xin + dres) * g + b ----------------
__global__ __launch_bounds__(256) void ln_kernel(const float* __restrict__ xin,
    const float* __restrict__ dres, const float* __restrict__ g,
    const float* __restrict__ bta, float* __restrict__ out) {
  const int row = blockIdx.x;
  const int t = threadIdx.x;
  __shared__ float red[256];
  const size_t base = (size_t)row * HH;
  const float v0 = xin[base + t] + dres[base + t];
  const float v1 = xin[base + 256 + t] + dres[base + 256 + t];
  const float v2 = xin[base + 512 + t] + dres[base + 512 + t];
  red[t] = v0 + v1 + v2; __syncthreads();
  for (int s = 128; s > 0; s >>= 1) { if (t < s) red[t] += red[t + s]; __syncthreads(); }
  const float mean = red[0] * (1.f / 768.f); __syncthreads();
  red[t] = v0 * v0 + v1 * v1 + v2 * v2; __syncthreads();
  for (int s = 128; s > 0; s >>= 1) { if (t < s) red[t] += red[t + s]; __syncthreads(); }
  const float var = red[0] * (1.f / 768.f) - mean * mean;
  const float rstd = rsqrtf(var + 1e-5f);
  out[base + t]       = (v0 - mean) * rstd * g[t]       + bta[t];
  out[base + 256 + t] = (v1 - mean) * rstd * g[256 + t] + bta[256 + t];
  out[base + 512 + t] = (v2 - mean) * rstd * g[512 + t] + bta[512 + t];
}

extern "C" void kernel_launch(void* const* d_in, const int* in_sizes, int n_in,
                              void* d_out, int out_size, void* d_ws, size_t ws_size,
                              hipStream_t stream) {
  const float* we      = (const float*)d_in[0];
  const float* be      = (const float*)d_in[1];
  const int*   seq_len = (const int*)d_in[2];
  const int*   lex_num = (const int*)d_in[3];
  const int*   pos_s   = (const int*)d_in[4];
  const int*   pos_e   = (const int*)d_in[5];
  const float* pe      = (const float*)d_in[6];
  const float* Wf1     = (const float*)d_in[7];
  const float* bf1     = (const float*)d_in[8];
  const float* Wf2     = (const float*)d_in[9];
  const float* bf2     = (const float*)d_in[10];
  const float* Wq = (const float*)d_in[11]; const float* bq = (const float*)d_in[12];
  const float* Wk = (const float*)d_in[13]; const float* bk = (const float*)d_in[14];
  const float* Wv = (const float*)d_in[15]; const float* bv = (const float*)d_in[16];
  const float* Wr = (const float*)d_in[17]; const float* br = (const float*)d_in[18];
  const float* uu = (const float*)d_in[19]; const float* vv = (const float*)d_in[20];
  const float* Wo = (const float*)d_in[21]; const float* bo = (const float*)d_in[22];
  const float* g1 = (const float*)d_in[23]; const float* be1 = (const float*)d_in[24];
  const float* W1 = (const float*)d_in[25]; const float* b1 = (const float*)d_in[26];
  const float* W2 = (const float*)d_in[27]; const float* b2 = (const float*)d_in[28];
  const float* g2 = (const float*)d_in[29]; const float* be2 = (const float*)d_in[30];

  // workspace layout (bytes, 16B aligned)
  char* ws = (char*)d_ws;
  float*  x     = (float*)(ws + 0);          // [384,768]
  float*  qkv   = (float*)(ws + 1179648);    // [384,2304]
  float*  PRb   = (float*)(ws + 4718592);    // [383,768]
  __half* Tt    = (__half*)(ws + 5898240);   // [4,384,3072] f16
  __half* BTf1  = (__half*)(ws + 15335424);  // [4,3072,768] f16, dead after T-gemm; aliased:
  float*  G     = (float*)(ws + 15335424);   //   [2,8,192,384]
  float*  parti = (float*)(ws + 20054016);   //   [4,73728,4]
  float*  w4    = (float*)(ws + 24772608);   //   [73728,4]
  __half* P     = (__half*)(ws + 25952256);  //   [2,8,192,192] f16
  float*  ctx   = (float*)(ws + 27131904);   //   [384,768]
  float*  ao    = (float*)(ws + 28311552);   //   [384,768]
  float*  x1    = (float*)(ws + 29491200);   //   [384,768]
  float*  ff    = (float*)(ws + 30670848);   //   [384,768]
  float*  fo    = (float*)(ws + 31850496);   //   [384,768]  (ends 33030144 < 34209792)
  __half* BTsq  = (__half*)(ws + 34209792);  // [7,768,768] f16: Wq,Wk,Wv,Wo,W1,W2,Wr
  h2*     wf2pG = (h2*)(ws + 42467328);
  h2*     bf1pG = (h2*)(ws + 42491904);
  float*  bqkv  = (float*)(ws + 42498048);   // [2304]
  float*  out   = (float*)d_out;

  const float* peu = pe + (size_t)JOFF * HH;
  const size_t SQ = (size_t)HH * HH;
  __half* WoT = BTsq + 3 * SQ; __half* W1T = BTsq + 4 * SQ;
  __half* W2T = BTsq + 5 * SQ; __half* WrT = BTsq + 6 * SQ;

  add_kernel<<<288, 256, 0, stream>>>((const float4*)we, (const float4*)be, (float4*)x, 73728);
  pack_kernel<<<1, 256, 0, stream>>>(Wf2, bf1, bq, bk, bv, wf2pG, bf1pG, bqkv);
  trans7<<<dim3(24, 24, 7), 256, 0, stream>>>(Wq, Wk, Wv, Wo, W1, W2, Wr, BTsq);
  trans_cvt<<<dim3(96, 24, 4), 256, 0, stream>>>(Wf1, BTf1, HH, H4);
  // PRb = peu @ Wr + br
  mfma_gemm<false, false><<<dim3(6, 3, 1), 256, 0, stream>>>(peu, WrT, br, PRb, NJ, HH, HH, 0, 0);
  // T_f = peu @ Wf1_f  (f16 tables, batched over f)
  mfma_gemm<true, false><<<dim3(24, 3, 4), 256, 0, stream>>>(peu, BTf1, nullptr, Tt,
      NJ, H4, HH, (long)H4 * HH, (long)NJP * H4);
  // fused q,k,v projection: qkv[384,2304]
  mfma_gemm<false, false><<<dim3(18, 3, 1), 256, 0, stream>>>(x, BTsq, bqkv, qkv,
      BB * SS, 3 * HH, HH, 0, 0);
  g2_kernel<<<128, 256, 0, stream>>>(qkv, PRb, vv, G);
  pairA_kernel<<<4608, 256, 0, stream>>>((const h2*)Tt, (const h8*)wf2pG, bf1pG,
      pos_s, pos_e, parti);
  pairB_kernel<<<288, 256, 0, stream>>>((const float4*)parti, bf2, (float4*)w4);
  attn2_kernel<<<128, 256, 0, stream>>>(qkv, uu, G, (const float4*)w4,
      pos_s, pos_e, seq_len, lex_num, P);
  ctx2_kernel<<<64, 256, 0, stream>>>(P, qkv, ctx);
  mfma_gemm<false, false><<<dim3(6, 3, 1), 256, 0, stream>>>(ctx, WoT, bo, ao, BB * SS, HH, HH, 0, 0);
  ln_kernel<<<BB * SS, 256, 0, stream>>>(x, ao, g1, be1, x1);
  mfma_gemm<false, true><<<dim3(6, 3, 1), 256, 0, stream>>>(x1, W1T, b1, ff, BB * SS, HH, HH, 0, 0);
  mfma_gemm<false, false><<<dim3(6, 3, 1), 256, 0, stream>>>(ff, W2T, b2, fo, BB * SS, HH, HH, 0, 0);
  ln_kernel<<<BB * SS, 256, 0, stream>>>(x1, fo, g2, be2, out);
}

// Round 6
// 441.529 us; speedup vs baseline: 2.2525x; 1.2170x over previous
//
#include <hip/hip_runtime.h>
#include <hip/hip_bf16.h>
#include <hip/hip_fp16.h>
#include <cstdint>

#define BB 2
#define SS 192
#define HH 768
#define NHH 8
#define DHH 96
#define H4 3072
#define NJ 383          // used pe rows: idx in [321, 703]
#define NJP 384
#define JOFF 321
#define NPAIR 73728     // 2*192*192
#define ATT_SCALE 0.10206207261596575f   // 1/sqrt(96)

typedef _Float16 h2 __attribute__((ext_vector_type(2)));
typedef _Float16 h4v __attribute__((ext_vector_type(4)));
typedef _Float16 h8 __attribute__((ext_vector_type(8)));
typedef float f4 __attribute__((ext_vector_type(4)));

// ---------------- x = a + b ----------------
__global__ __launch_bounds__(256) void add_kernel(const float4* __restrict__ a,
    const float4* __restrict__ b, float4* __restrict__ o, int n4) {
  int i = blockIdx.x * 256 + threadIdx.x;
  if (i < n4) {
    float4 va = a[i], vb = b[i];
    o[i] = make_float4(va.x + vb.x, va.y + vb.y, va.z + vb.z, va.w + vb.w);
  }
}

// ---------------- transpose + f32->f16 (for Wf1): dst[n][k] = src[k][n] ----------------
__global__ __launch_bounds__(256) void trans_cvt(const float* __restrict__ src,
    __half* __restrict__ dst, int K, int N) {
  __shared__ float tile[32][33];
  const size_t zoff = (size_t)blockIdx.z * K * N;
  src += zoff; dst += zoff;
  const int x = blockIdx.x * 32, y = blockIdx.y * 32;
  const int tx = threadIdx.x & 31, ty = threadIdx.x >> 5;
#pragma unroll
  for (int i = 0; i < 4; ++i)
    tile[ty + 8 * i][tx] = src[(size_t)(y + ty + 8 * i) * N + x + tx];
  __syncthreads();
#pragma unroll
  for (int i = 0; i < 4; ++i)
    dst[(size_t)(x + ty + 8 * i) * K + y + tx] = __float2half(tile[tx][ty + 8 * i]);
}

// ---------------- 7 square-weight transposes in one launch ----------------
__global__ __launch_bounds__(256) void trans7(const float* __restrict__ s0,
    const float* __restrict__ s1, const float* __restrict__ s2, const float* __restrict__ s3,
    const float* __restrict__ s4, const float* __restrict__ s5, const float* __restrict__ s6,
    __half* __restrict__ dstBase) {
  __shared__ float tile[32][33];
  const int z = blockIdx.z;
  const float* src;
  switch (z) {
    case 0: src = s0; break; case 1: src = s1; break; case 2: src = s2; break;
    case 3: src = s3; break; case 4: src = s4; break; case 5: src = s5; break;
    default: src = s6; break;
  }
  __half* dst = dstBase + (size_t)z * HH * HH;
  const int x = blockIdx.x * 32, y = blockIdx.y * 32;
  const int tx = threadIdx.x & 31, ty = threadIdx.x >> 5;
#pragma unroll
  for (int i = 0; i < 4; ++i)
    tile[ty + 8 * i][tx] = src[(size_t)(y + ty + 8 * i) * HH + x + tx];
  __syncthreads();
#pragma unroll
  for (int i = 0; i < 4; ++i)
    dst[(size_t)(x + ty + 8 * i) * HH + y + tx] = __float2half(tile[tx][ty + 8 * i]);
}

// ---------------- MFMA GEMM: C[M,N] = A[M,K](f32) @ BT[N,K](f16)^T, BK=64 pipelined ----
template<bool OUT_HALF, bool RELU>
__global__ __launch_bounds__(256) void mfma_gemm(const float* __restrict__ A,
    const __half* __restrict__ BT, const float* __restrict__ bias, void* __restrict__ Cv,
    int M, int N, int K, long sB, long sC) {
  __shared__ _Float16 As[128][72];
  __shared__ _Float16 Bs[128][72];
  const int t = threadIdx.x;
  const int z = blockIdx.z;
  const __half* Bb = BT + (size_t)z * sB;
  const int bm = blockIdx.y * 128, bn = blockIdx.x * 128;
  const int wave = t >> 6, lane = t & 63;
  const int wr = (wave >> 1) * 64, wc = (wave & 1) * 64;
  const int lrow = lane & 15, khalf = lane >> 4;
  const int arow = t >> 4, acol = (t & 15) << 2;
  const int brow = t >> 3, bcol = (t & 7) << 3;
  f4 acc[4][4] = {};
  const int nk = K >> 6;
  float4 ra[8]; h8 rb[4];

#define LOAD_TILE(kt) { \
  _Pragma("unroll") for (int i = 0; i < 8; ++i) { \
    const int row = arow + (i << 4); \
    if (bm + row < M) ra[i] = *(const float4*)(A + (size_t)(bm + row) * K + (size_t)(kt) * 64 + acol); \
    else ra[i] = make_float4(0.f, 0.f, 0.f, 0.f); } \
  _Pragma("unroll") for (int i = 0; i < 4; ++i) { \
    const int row = brow + (i << 5); \
    rb[i] = *(const h8*)(Bb + (size_t)(bn + row) * K + (size_t)(kt) * 64 + bcol); } }

#define STORE_TILE() { \
  _Pragma("unroll") for (int i = 0; i < 8; ++i) { \
    const int row = arow + (i << 4); \
    h4v hv = {(_Float16)ra[i].x, (_Float16)ra[i].y, (_Float16)ra[i].z, (_Float16)ra[i].w}; \
    *(h4v*)&As[row][acol] = hv; } \
  _Pragma("unroll") for (int i = 0; i < 4; ++i) { \
    const int row = brow + (i << 5); \
    *(h8*)&Bs[row][bcol] = rb[i]; } }

  LOAD_TILE(0)
  STORE_TILE()
  __syncthreads();
  for (int kt = 0; kt < nk; ++kt) {
    const bool more = (kt + 1 < nk);
    if (more) { LOAD_TILE(kt + 1) }
#pragma unroll
    for (int ks = 0; ks < 2; ++ks) {
      h8 af[4], bf[4];
#pragma unroll
      for (int mi = 0; mi < 4; ++mi) af[mi] = *(const h8*)&As[wr + mi * 16 + lrow][ks * 32 + (khalf << 3)];
#pragma unroll
      for (int ni = 0; ni < 4; ++ni) bf[ni] = *(const h8*)&Bs[wc + ni * 16 + lrow][ks * 32 + (khalf << 3)];
#pragma unroll
      for (int mi = 0; mi < 4; ++mi)
#pragma unroll
        for (int ni = 0; ni < 4; ++ni)
          acc[mi][ni] = __builtin_amdgcn_mfma_f32_16x16x32_f16(af[mi], bf[ni], acc[mi][ni], 0, 0, 0);
    }
    __syncthreads();
    if (more) { STORE_TILE() }
    __syncthreads();
  }
#undef LOAD_TILE
#undef STORE_TILE
  const int crow0 = (lane >> 4) << 2;
  const int ccol = lane & 15;
#pragma unroll
  for (int mi = 0; mi < 4; ++mi) {
#pragma unroll
    for (int r = 0; r < 4; ++r) {
      const int row = bm + wr + mi * 16 + crow0 + r;
      if (row >= M) continue;
#pragma unroll
      for (int ni = 0; ni < 4; ++ni) {
        const int col = bn + wc + ni * 16 + ccol;
        float v = acc[mi][ni][r];
        if (bias) v += bias[col];
        if (RELU) v = fmaxf(v, 0.f);
        if (OUT_HALF) ((__half*)Cv)[(size_t)z * sC + (size_t)row * N + col] = __float2half(v);
        else          ((float*)Cv)[(size_t)z * sC + (size_t)row * N + col] = v;
      }
    }
  }
}

// ---------------- pack wf2/bf1 (half2) + bqkv concat ----------------
__global__ __launch_bounds__(256) void pack_kernel(const float* __restrict__ wf2,
    const float* __restrict__ bf1, const float* __restrict__ bq, const float* __restrict__ bk,
    const float* __restrict__ bv, h2* __restrict__ wf2pG, h2* __restrict__ bf1pG,
    float* __restrict__ bqkv) {
  for (int i = threadIdx.x; i < 6144; i += 256) {
    const int cw = i >> 2, f = i & 3;
    h2 v = {(_Float16)wf2[8 * cw + f], (_Float16)wf2[8 * cw + 4 + f]};
    wf2pG[i] = v;
  }
  for (int i = threadIdx.x; i < 1536; i += 256) {
    h2 v = {(_Float16)bf1[2 * i], (_Float16)bf1[2 * i + 1]};
    bf1pG[i] = v;
  }
  for (int i = threadIdx.x; i < 768; i += 256) {
    bqkv[i] = bq[i]; bqkv[768 + i] = bk[i]; bqkv[1536 + i] = bv[i];
  }
}

// ---------------- pairJ: precompute packed j-tuples per pair ----------------
__global__ __launch_bounds__(256) void pairJ_kernel(const int* __restrict__ pos_s,
    const int* __restrict__ pos_e, ushort* __restrict__ jtab) {
  const int p = blockIdx.x * 256 + threadIdx.x;   // grid 288*256 = 73728 exact
  const int b = p / 36864;
  const int rem = p - b * 36864;
  const int qq = rem / 192;
  const int kk = rem - qq * 192;
  const int psq = pos_s[b * 192 + qq], peq = pos_e[b * 192 + qq];
  const int psk = pos_s[b * 192 + kk], pek = pos_e[b * 192 + kk];
  ushort4 j;
  j.x = (ushort)min(max(psq - psk + 191, 0), NJ - 1);
  j.y = (ushort)min(max(psq - pek + 191, 0), NJ - 1);
  j.z = (ushort)min(max(peq - psk + 191, 0), NJ - 1);
  j.w = (ushort)min(max(peq - pek + 191, 0), NJ - 1);
  *(ushort4*)(jtab + 4 * p) = j;
}

// ---------------- G[b,n,q,j] = dot(q+v, PRb[j,n,:]) — LDS-staged, reg-tiled ----------------
// grid 128: blk = ((b*8+n)*8 + jt), jt covers 48 j
__global__ __launch_bounds__(256) void g2_kernel(const float* __restrict__ qkv,
    const float* __restrict__ PRb, const float* __restrict__ vv, float* __restrict__ G) {
  __shared__ float Qv[192][100];
  __shared__ float PRs[48][100];
  const int blk = blockIdx.x;
  const int jt = blk & 7, n = (blk >> 3) & 7, b = blk >> 6;
  const int j0 = jt * 48;
  const int t = threadIdx.x;
  for (int i = t; i < 4608; i += 256) {
    const int q = i / 24, c = (i % 24) * 4;
    float4 v = *(const float4*)(qkv + (size_t)(b * 192 + q) * 2304 + n * 96 + c);
    const float4 vb = *(const float4*)(vv + n * 96 + c);
    Qv[q][c] = v.x + vb.x; Qv[q][c + 1] = v.y + vb.y;
    Qv[q][c + 2] = v.z + vb.z; Qv[q][c + 3] = v.w + vb.w;
  }
  for (int i = t; i < 1152; i += 256) {
    const int jr = i / 24, c = (i % 24) * 4;
    const int j = min(j0 + jr, NJ - 1);
    *(f4*)&PRs[jr][c] = *(const f4*)(PRb + (size_t)j * 768 + n * 96 + c);
  }
  __syncthreads();
  const int qt = t >> 4, jt2 = t & 15;
  const int qb0 = qt * 12;
  float acc[12][3] = {};
  for (int dq = 0; dq < 24; ++dq) {
    const f4 p0 = *(const f4*)&PRs[jt2][dq * 4];
    const f4 p1 = *(const f4*)&PRs[jt2 + 16][dq * 4];
    const f4 p2 = *(const f4*)&PRs[jt2 + 32][dq * 4];
#pragma unroll
    for (int qi = 0; qi < 12; ++qi) {
      const f4 qv = *(const f4*)&Qv[qb0 + qi][dq * 4];
      acc[qi][0] += qv.x * p0.x + qv.y * p0.y + qv.z * p0.z + qv.w * p0.w;
      acc[qi][1] += qv.x * p1.x + qv.y * p1.y + qv.z * p1.z + qv.w * p1.w;
      acc[qi][2] += qv.x * p2.x + qv.y * p2.y + qv.z * p2.z + qv.w * p2.w;
    }
  }
  float* Grow = G + (size_t)(b * 8 + n) * 192 * NJP;
#pragma unroll
  for (int qi = 0; qi < 12; ++qi)
#pragma unroll
    for (int ji = 0; ji < 3; ++ji)
      Grow[(size_t)(qb0 + qi) * NJP + j0 + jt2 + 16 * ji] = acc[qi][ji];
}

// ---------------- pairA v2: 16-lane pair-groups, coalesced, reg-resident weights -------
// grid 4608; chunk = (blk%8)>>1 (XCD-affine); 64 pairs per block, 4 per 16-lane group.
__global__ __launch_bounds__(256) void pairA_kernel(const h2* __restrict__ Tt,
    const h8* __restrict__ wf2pG, const h2* __restrict__ bf1pG,
    const ushort* __restrict__ jtab, float* __restrict__ partials) {
  const int blk = blockIdx.x;
  const int chunk = (blk & 7) >> 1;
  const int cbase = chunk * 384;
  const int t = threadIdx.x;
  const int grp = t >> 4, l16 = t & 15;
  const int pbase = (blk >> 3) * 128 + (blk & 1) * 64;
  const h2 zero2 = {(_Float16)0.f, (_Float16)0.f};
  // preload this lane's wf2/bf1 granules (channels cw = (l16+16s)*4+v) into registers
  h8 Wr[3][4]; h2 B1[3][4];
#pragma unroll
  for (int s = 0; s < 3; ++s)
#pragma unroll
    for (int v = 0; v < 4; ++v) {
      const int cw = (l16 + 16 * s) * 4 + v;
      Wr[s][v] = wf2pG[cbase + cw];
      B1[s][v] = bf1pG[cbase + cw];
    }
  const h2* Tc = Tt + cbase;
#pragma unroll 2
  for (int i = 0; i < 4; ++i) {
    const int p = pbase + i * 16 + grp;
    const ushort4 j = *(const ushort4*)(jtab + 4 * p);
    const h8* r0 = (const h8*)(Tc + (size_t)j.x * 1536);
    const h8* r1 = (const h8*)(Tc + (size_t)(NJP + j.y) * 1536);
    const h8* r2 = (const h8*)(Tc + (size_t)(2 * NJP + j.z) * 1536);
    const h8* r3 = (const h8*)(Tc + (size_t)(3 * NJP + j.w) * 1536);
    h2 c0 = zero2, c1 = zero2, c2 = zero2, c3 = zero2;
#pragma unroll
    for (int s = 0; s < 3; ++s) {
      const int g = l16 + 16 * s;
      union { h8 v; h2 p[4]; } L0, L1, L2, L3;
      L0.v = r0[g]; L1.v = r1[g]; L2.v = r2[g]; L3.v = r3[g];
#pragma unroll
      for (int v = 0; v < 4; ++v) {
        h2 sv = L0.p[v] + L1.p[v];
        sv = sv + L2.p[v];
        sv = sv + L3.p[v];
        sv = sv + B1[s][v];
        sv = __builtin_elementwise_max(sv, zero2);
        union { h8 v; h2 p[4]; } W; W.v = Wr[s][v];
        c0 += sv * W.p[0];
        c1 += sv * W.p[1];
        c2 += sv * W.p[2];
        c3 += sv * W.p[3];
      }
    }
    float a0 = (float)c0.x + (float)c0.y;
    float a1 = (float)c1.x + (float)c1.y;
    float a2 = (float)c2.x + (float)c2.y;
    float a3 = (float)c3.x + (float)c3.y;
#pragma unroll
    for (int off = 8; off > 0; off >>= 1) {
      a0 += __shfl_xor(a0, off, 16);
      a1 += __shfl_xor(a1, off, 16);
      a2 += __shfl_xor(a2, off, 16);
      a3 += __shfl_xor(a3, off, 16);
    }
    if (l16 < 4) {
      const float sel = (l16 == 0) ? a0 : (l16 == 1) ? a1 : (l16 == 2) ? a2 : a3;
      partials[((size_t)chunk * NPAIR + p) * 4 + l16] = sel;
    }
  }
}

// ---------------- pairB: combine chunk partials -> w4 softmax ----------------
__global__ __launch_bounds__(256) void pairB_kernel(const float4* __restrict__ partials,
    const float* __restrict__ bf2, float4* __restrict__ w4) {
  const int p = blockIdx.x * 256 + threadIdx.x;
  const float4 s0 = partials[p];
  const float4 s1 = partials[NPAIR + p];
  const float4 s2 = partials[2 * NPAIR + p];
  const float4 s3 = partials[3 * NPAIR + p];
  const float a0 = s0.x + s1.x + s2.x + s3.x + bf2[0];
  const float a1 = s0.y + s1.y + s2.y + s3.y + bf2[1];
  const float a2 = s0.z + s1.z + s2.z + s3.z + bf2[2];
  const float a3 = s0.w + s1.w + s2.w + s3.w + bf2[3];
  const float mx = fmaxf(fmaxf(a0, a1), fmaxf(a2, a3));
  const float e0 = __expf(a0 - mx), e1 = __expf(a1 - mx);
  const float e2 = __expf(a2 - mx), e3 = __expf(a3 - mx);
  const float inv = 1.f / (e0 + e1 + e2 + e3);
  w4[p] = make_float4(e0 * inv, e1 * inv, e2 * inv, e3 * inv);
}

// ---------------- attn2: AC (LDS-staged) + BD (w4·G from LDS) + softmax -> pattn f16 ----
// grid 256: blk = ((b*8+n)*16 + qt), 12 q rows per block
__global__ __launch_bounds__(256) void attn2_kernel(const float* __restrict__ qkv,
    const float* __restrict__ uu, const float* __restrict__ G,
    const float4* __restrict__ w4, const int* __restrict__ pos_s, const int* __restrict__ pos_e,
    const int* __restrict__ seq_len, const int* __restrict__ lex_num,
    __half* __restrict__ P) {
  __shared__ float Ks[192][100];
  __shared__ float Qs[12][100];
  __shared__ float Gs[12][388];
  __shared__ int poss[192], pose[192];
  const int blk = blockIdx.x;
  const int qt = blk & 15, n = (blk >> 4) & 7, b = blk >> 7;
  const int q0 = qt * 12;
  const int t = threadIdx.x;
  for (int i = t; i < 4608; i += 256) {
    const int k = i / 24, c = (i % 24) * 4;
    *(f4*)&Ks[k][c] = *(const f4*)(qkv + (size_t)(b * 192 + k) * 2304 + 768 + n * 96 + c);
  }
  for (int i = t; i < 288; i += 256) {
    const int qi = i / 24, c = (i % 24) * 4;
    float4 v = *(const float4*)(qkv + (size_t)(b * 192 + q0 + qi) * 2304 + n * 96 + c);
    const float4 ub = *(const float4*)(uu + n * 96 + c);
    Qs[qi][c] = v.x + ub.x; Qs[qi][c + 1] = v.y + ub.y;
    Qs[qi][c + 2] = v.z + ub.z; Qs[qi][c + 3] = v.w + ub.w;
  }
  for (int i = t; i < 1152; i += 256) {
    const int qi = i / 96, c = (i % 96) * 4;
    *(f4*)&Gs[qi][c] = *(const f4*)(G + ((size_t)(b * 8 + n) * 192 + q0 + qi) * NJP + c);
  }
  for (int i = t; i < 192; i += 256) { poss[i] = pos_s[b * 192 + i]; pose[i] = pos_e[b * 192 + i]; }
  __syncthreads();
  const int wave = t >> 6, lane = t & 63;
  const int qw = wave * 3;
  float ac[3][3] = {};
  for (int dq = 0; dq < 24; ++dq) {
    const f4 kv0 = *(const f4*)&Ks[lane][dq * 4];
    const f4 kv1 = *(const f4*)&Ks[lane + 64][dq * 4];
    const f4 kv2 = *(const f4*)&Ks[lane + 128][dq * 4];
#pragma unroll
    for (int qi = 0; qi < 3; ++qi) {
      const f4 qv = *(const f4*)&Qs[qw + qi][dq * 4];
      ac[qi][0] += qv.x * kv0.x + qv.y * kv0.y + qv.z * kv0.z + qv.w * kv0.w;
      ac[qi][1] += qv.x * kv1.x + qv.y * kv1.y + qv.z * kv1.z + qv.w * kv1.w;
      ac[qi][2] += qv.x * kv2.x + qv.y * kv2.y + qv.z * kv2.z + qv.w * kv2.w;
    }
  }
  const int vbnd = seq_len[b] + lex_num[b];
#pragma unroll
  for (int qi = 0; qi < 3; ++qi) {
    const int qg = q0 + qw + qi;
    const int psq = poss[qg], peq = pose[qg];
    float v[3];
#pragma unroll
    for (int ki = 0; ki < 3; ++ki) {
      const int k = lane + 64 * ki;
      const int psk = poss[k], pek = pose[k];
      const int jss = min(max(psq - psk + 191, 0), NJ - 1);
      const int jse = min(max(psq - pek + 191, 0), NJ - 1);
      const int jes = min(max(peq - psk + 191, 0), NJ - 1);
      const int jee = min(max(peq - pek + 191, 0), NJ - 1);
      const float4 w = w4[(size_t)b * 36864 + (size_t)qg * 192 + k];
      const float bd = w.x * Gs[qw + qi][jss] + w.y * Gs[qw + qi][jse]
                     + w.z * Gs[qw + qi][jes] + w.w * Gs[qw + qi][jee];
      const float a = (ac[qi][ki] + bd) * ATT_SCALE;
      v[ki] = (k < vbnd) ? a : -1e15f;
    }
    float mx = fmaxf(fmaxf(v[0], v[1]), v[2]);
#pragma unroll
    for (int off = 1; off < 64; off <<= 1) mx = fmaxf(mx, __shfl_xor(mx, off, 64));
    const float e0 = __expf(v[0] - mx), e1 = __expf(v[1] - mx), e2 = __expf(v[2] - mx);
    float sm = e0 + e1 + e2;
#pragma unroll
    for (int off = 1; off < 64; off <<= 1) sm += __shfl_xor(sm, off, 64);
    const float inv = 1.f / sm;
    __half* pr = P + ((size_t)(b * 8 + n) * 192 + qg) * 192;
    pr[lane] = __float2half(e0 * inv);
    pr[lane + 64] = __float2half(e1 * inv);
    pr[lane + 128] = __float2half(e2 * inv);
  }
}

// ---------------- ctx2: ctx[b,q,n*96+d] = sum_k P[b,n,q,k] * V[b,k,n*96+d] ----------------
// grid 64: blk = ((b*8+n)*4 + qt), 48 q rows per block
__global__ __launch_bounds__(256) void ctx2_kernel(const __half* __restrict__ P,
    const float* __restrict__ qkv, float* __restrict__ ctx) {
  __shared__ float Vs[192][100];
  __shared__ float Ps[48][196];
  const int blk = blockIdx.x;
  const int qt = blk & 3, n = (blk >> 2) & 7, b = blk >> 5;
  const int q0 = qt * 48;
  const int t = threadIdx.x;
  for (int i = t; i < 4608; i += 256) {
    const int k = i / 24, c = (i % 24) * 4;
    *(f4*)&Vs[k][c] = *(const f4*)(qkv + (size_t)(b * 192 + k) * 2304 + 1536 + n * 96 + c);
  }
  const __half* Pb = P + ((size_t)(b * 8 + n) * 192 + q0) * 192;
  for (int i = t; i < 4608; i += 256) {
    const int qi = i / 96, c = (i % 96) * 2;
    const h2 pv = *(const h2*)(Pb + (size_t)qi * 192 + c);
    Ps[qi][c] = (float)pv.x; Ps[qi][c + 1] = (float)pv.y;
  }
  __syncthreads();
  const int qt2 = t >> 5, dt = t & 31;
  const int qb0 = qt2 * 6;
  float acc[6][3] = {};
  for (int k4 = 0; k4 < 48; ++k4) {
    const int k = k4 * 4;
    f4 pq[6];
#pragma unroll
    for (int qi = 0; qi < 6; ++qi) pq[qi] = *(const f4*)&Ps[qb0 + qi][k];
#pragma unroll
    for (int kk = 0; kk < 4; ++kk) {
      const float v0 = Vs[k + kk][dt];
      const float v1 = Vs[k + kk][dt + 32];
      const float v2 = Vs[k + kk][dt + 64];
#pragma unroll
      for (int qi = 0; qi < 6; ++qi) {
        const float pv = pq[qi][kk];
        acc[qi][0] += pv * v0; acc[qi][1] += pv * v1; acc[qi][2] += pv * v2;
      }
    }
  }
#pragma unroll
  for (int qi = 0; qi < 6; ++qi) {
    float* cr = ctx + (size_t)(b * 192 + q0 + qb0 + qi) * 768 + n * 96;
    cr[dt] = acc[qi][0]; cr[dt + 32] = acc[qi][1]; cr[dt + 64] = acc[qi][2];
  }
}

// ---------------- out = LayerNorm(xin + dres) * g + b ----------------
__global__ __launch_bounds__(256) void ln_kernel(const float* __restrict__ xin,
    const float* __restrict__ dres, const float* __restrict__ g,
    const float* __restrict__ bta, float* __restrict__ out) {
  const int row = blockIdx.x;
  const int t = threadIdx.x;
  __shared__ float red[256];
  const size_t base = (size_t)row * HH;
  const float v0 = xin[base + t] + dres[base + t];
  const float v1 = xin[base + 256 + t] + dres[base + 256 + t];
  const float v2 = xin[base + 512 + t] + dres[base + 512 + t];
  red[t] = v0 + v1 + v2; __syncthreads();
  for (int s = 128; s > 0; s >>= 1) { if (t < s) red[t] += red[t + s]; __syncthreads(); }
  const float mean = red[0] * (1.f / 768.f); __syncthreads();
  red[t] = v0 * v0 + v1 * v1 + v2 * v2; __syncthreads();
  for (int s = 128; s > 0; s >>= 1) { if (t < s) red[t] += red[t + s]; __syncthreads(); }
  const float var = red[0] * (1.f / 768.f) - mean * mean;
  const float rstd = rsqrtf(var + 1e-5f);
  out[base + t]       = (v0 - mean) * rstd * g[t]       + bta[t];
  out[base + 256 + t] = (v1 - mean) * rstd * g[256 + t] + bta[256 + t];
  out[base + 512 + t] = (v2 - mean) * rstd * g[512 + t] + bta[512 + t];
}

extern "C" void kernel_launch(void* const* d_in, const int* in_sizes, int n_in,
                              void* d_out, int out_size, void* d_ws, size_t ws_size,
                              hipStream_t stream) {
  const float* we      = (const float*)d_in[0];
  const float* be      = (const float*)d_in[1];
  const int*   seq_len = (const int*)d_in[2];
  const int*   lex_num = (const int*)d_in[3];
  const int*   pos_s   = (const int*)d_in[4];
  const int*   pos_e   = (const int*)d_in[5];
  const float* pe      = (const float*)d_in[6];
  const float* Wf1     = (const float*)d_in[7];
  const float* bf1     = (const float*)d_in[8];
  const float* Wf2     = (const float*)d_in[9];
  const float* bf2     = (const float*)d_in[10];
  const float* Wq = (const float*)d_in[11]; const float* bq = (const float*)d_in[12];
  const float* Wk = (const float*)d_in[13]; const float* bk = (const float*)d_in[14];
  const float* Wv = (const float*)d_in[15]; const float* bv = (const float*)d_in[16];
  const float* Wr = (const float*)d_in[17]; const float* br = (const float*)d_in[18];
  const float* uu = (const float*)d_in[19]; const float* vv = (const float*)d_in[20];
  const float* Wo = (const float*)d_in[21]; const float* bo = (const float*)d_in[22];
  const float* g1 = (const float*)d_in[23]; const float* be1 = (const float*)d_in[24];
  const float* W1 = (const float*)d_in[25]; const float* b1 = (const float*)d_in[26];
  const float* W2 = (const float*)d_in[27]; const float* b2 = (const float*)d_in[28];
  const float* g2 = (const float*)d_in[29]; const float* be2 = (const float*)d_in[30];

  // workspace layout (bytes, 16B aligned)
  char* ws = (char*)d_ws;
  float*  x     = (float*)(ws + 0);          // [384,768]
  float*  qkv   = (float*)(ws + 1179648);    // [384,2304]
  float*  PRb   = (float*)(ws + 4718592);    // [383,768]
  __half* Tt    = (__half*)(ws + 5898240);   // [4,384,3072] f16
  __half* BTf1  = (__half*)(ws + 15335424);  // [4,3072,768] f16, dead after T-gemm; aliased:
  float*  G     = (float*)(ws + 15335424);   //   [2,8,192,384]
  float*  parti = (float*)(ws + 20054016);   //   [4,73728,4]
  float*  w4    = (float*)(ws + 24772608);   //   [73728,4]
  __half* P     = (__half*)(ws + 25952256);  //   [2,8,192,192] f16
  float*  ctx   = (float*)(ws + 27131904);   //   [384,768]
  float*  ao    = (float*)(ws + 28311552);   //   [384,768]
  float*  x1    = (float*)(ws + 29491200);   //   [384,768]
  float*  ff    = (float*)(ws + 30670848);   //   [384,768]
  float*  fo    = (float*)(ws + 31850496);   //   [384,768] (ends 33030144)
  ushort* jtab  = (ushort*)(ws + 33030144);  //   [73728,4] u16 (ends 33619968 < 34209792)
  __half* BTsq  = (__half*)(ws + 34209792);  // [7,768,768] f16: Wq,Wk,Wv,Wo,W1,W2,Wr
  h2*     wf2pG = (h2*)(ws + 42467328);
  h2*     bf1pG = (h2*)(ws + 42491904);
  float*  bqkv  = (float*)(ws + 42498048);   // [2304]
  float*  out   = (float*)d_out;

  const float* peu = pe + (size_t)JOFF * HH;
  const size_t SQ = (size_t)HH * HH;
  __half* WoT = BTsq + 3 * SQ; __half* W1T = BTsq + 4 * SQ;
  __half* W2T = BTsq + 5 * SQ; __half* WrT = BTsq + 6 * SQ;

  add_kernel<<<288, 256, 0, stream>>>((const float4*)we, (const float4*)be, (float4*)x, 73728);
  pack_kernel<<<1, 256, 0, stream>>>(Wf2, bf1, bq, bk, bv, wf2pG, bf1pG, bqkv);
  trans7<<<dim3(24, 24, 7), 256, 0, stream>>>(Wq, Wk, Wv, Wo, W1, W2, Wr, BTsq);
  trans_cvt<<<dim3(96, 24, 4), 256, 0, stream>>>(Wf1, BTf1, HH, H4);
  // PRb = peu @ Wr + br
  mfma_gemm<false, false><<<dim3(6, 3, 1), 256, 0, stream>>>(peu, WrT, br, PRb, NJ, HH, HH, 0, 0);
  // T_f = peu @ Wf1_f  (f16 tables, batched over f)
  mfma_gemm<true, false><<<dim3(24, 3, 4), 256, 0, stream>>>(peu, BTf1, nullptr, Tt,
      NJ, H4, HH, (long)H4 * HH, (long)NJP * H4);
  // pairJ after T-gemm (jtab aliases BTf1 tail)
  pairJ_kernel<<<288, 256, 0, stream>>>(pos_s, pos_e, jtab);
  // fused q,k,v projection: qkv[384,2304]
  mfma_gemm<false, false><<<dim3(18, 3, 1), 256, 0, stream>>>(x, BTsq, bqkv, qkv,
      BB * SS, 3 * HH, HH, 0, 0);
  g2_kernel<<<128, 256, 0, stream>>>(qkv, PRb, vv, G);
  pairA_kernel<<<4608, 256, 0, stream>>>((const h2*)Tt, (const h8*)wf2pG, bf1pG,
      jtab, parti);
  pairB_kernel<<<288, 256, 0, stream>>>((const float4*)parti, bf2, (float4*)w4);
  attn2_kernel<<<256, 256, 0, stream>>>(qkv, uu, G, (const float4*)w4,
      pos_s, pos_e, seq_len, lex_num, P);
  ctx2_kernel<<<64, 256, 0, stream>>>(P, qkv, ctx);
  mfma_gemm<false, false><<<dim3(6, 3, 1), 256, 0, stream>>>(ctx, WoT, bo, ao, BB * SS, HH, HH, 0, 0);
  ln_kernel<<<BB * SS, 256, 0, stream>>>(x, ao, g1, be1, x1);
  mfma_gemm<false, true><<<dim3(6, 3, 1), 256, 0, stream>>>(x1, W1T, b1, ff, BB * SS, HH, HH, 0, 0);
  mfma_gemm<false, false><<<dim3(6, 3, 1), 256, 0, stream>>>(ff, W2T, b2, fo, BB * SS, HH, HH, 0, 0);
  ln_kernel<<<BB * SS, 256, 0, stream>>>(x1, fo, g2, be2, out);
}

// Round 8
// 405.744 us; speedup vs baseline: 2.4512x; 1.0882x over previous
//
#include <hip/hip_runtime.h>
#include <hip/hip_bf16.h>
#include <hip/hip_fp16.h>
#include <cstdint>

#define BB 2
#define SS 192
#define HH 768
#define NHH 8
#define DHH 96
#define H4 3072
#define NJ 383          // used pe rows: idx in [321, 703]
#define NJP 384
#define JOFF 321
#define NPAIR 73728     // 2*192*192
#define ATT_SCALE 0.10206207261596575f   // 1/sqrt(96)

typedef _Float16 h2 __attribute__((ext_vector_type(2)));
typedef _Float16 h4v __attribute__((ext_vector_type(4)));
typedef _Float16 h8 __attribute__((ext_vector_type(8)));
typedef float f4 __attribute__((ext_vector_type(4)));

// ================= prep: add + pack + trans7 + trans_cvt in one launch =================
// blocks [0,288): x = we + be          (288*256 float4 = 73728)
// block  288    : pack wf2/bf1/bqkv
// [289,4321)    : trans7  (7 square weights -> BTsq f16^T)
// [4321,13537)  : trans_cvt Wf1 -> BTf1 f16^T (4 slices)
__global__ __launch_bounds__(256) void prep_kernel(
    const float4* __restrict__ we, const float4* __restrict__ be, float4* __restrict__ xb,
    const float* __restrict__ wf2, const float* __restrict__ bf1,
    const float* __restrict__ bq, const float* __restrict__ bk, const float* __restrict__ bv,
    h2* __restrict__ wf2pG, h2* __restrict__ bf1pG, float* __restrict__ bqkv,
    const float* __restrict__ s0, const float* __restrict__ s1, const float* __restrict__ s2,
    const float* __restrict__ s3, const float* __restrict__ s4, const float* __restrict__ s5,
    const float* __restrict__ s6, __half* __restrict__ BTsq,
    const float* __restrict__ Wf1, __half* __restrict__ BTf1) {
  __shared__ float tile[32][33];
  const int blk = blockIdx.x;
  const int t = threadIdx.x;
  if (blk < 288) {
    const int i = blk * 256 + t;
    float4 va = we[i], vb = be[i];
    xb[i] = make_float4(va.x + vb.x, va.y + vb.y, va.z + vb.z, va.w + vb.w);
  } else if (blk == 288) {
    for (int i = t; i < 6144; i += 256) {
      const int cw = i >> 2, f = i & 3;
      h2 v = {(_Float16)wf2[8 * cw + f], (_Float16)wf2[8 * cw + 4 + f]};
      wf2pG[i] = v;
    }
    for (int i = t; i < 1536; i += 256) {
      h2 v = {(_Float16)bf1[2 * i], (_Float16)bf1[2 * i + 1]};
      bf1pG[i] = v;
    }
    for (int i = t; i < 768; i += 256) {
      bqkv[i] = bq[i]; bqkv[768 + i] = bk[i]; bqkv[1536 + i] = bv[i];
    }
  } else if (blk < 4321) {
    const int i7 = blk - 289;
    const int z = i7 / 576, rem = i7 % 576;
    const int y = (rem / 24) * 32, x = (rem % 24) * 32;
    const float* src;
    switch (z) {
      case 0: src = s0; break; case 1: src = s1; break; case 2: src = s2; break;
      case 3: src = s3; break; case 4: src = s4; break; case 5: src = s5; break;
      default: src = s6; break;
    }
    __half* dst = BTsq + (size_t)z * HH * HH;
    const int tx = t & 31, ty = t >> 5;
#pragma unroll
    for (int i = 0; i < 4; ++i)
      tile[ty + 8 * i][tx] = src[(size_t)(y + ty + 8 * i) * HH + x + tx];
    __syncthreads();
#pragma unroll
    for (int i = 0; i < 4; ++i)
      dst[(size_t)(x + ty + 8 * i) * HH + y + tx] = __float2half(tile[tx][ty + 8 * i]);
  } else {
    const int ic = blk - 4321;
    const int z = ic / 2304, rem = ic % 2304;
    const int y = (rem / 96) * 32, x = (rem % 96) * 32;
    const float* src = Wf1 + (size_t)z * HH * H4;
    __half* dst = BTf1 + (size_t)z * HH * H4;
    const int tx = t & 31, ty = t >> 5;
#pragma unroll
    for (int i = 0; i < 4; ++i)
      tile[ty + 8 * i][tx] = src[(size_t)(y + ty + 8 * i) * H4 + x + tx];
    __syncthreads();
#pragma unroll
    for (int i = 0; i < 4; ++i)
      dst[(size_t)(x + ty + 8 * i) * HH + y + tx] = __float2half(tile[tx][ty + 8 * i]);
  }
}

// ================= MFMA GEMM body (BK=64, reg-prefetch pipelined) =================
template<bool OUT_HALF, bool RELU>
__device__ __forceinline__ void gemm_body(_Float16 (*As)[72], _Float16 (*Bs)[72],
    const float* __restrict__ A, const __half* __restrict__ Bb, const float* __restrict__ bias,
    void* __restrict__ Cv, int M, int N, int K, int bm, int bn, int t) {
  const int wave = t >> 6, lane = t & 63;
  const int wr = (wave >> 1) * 64, wc = (wave & 1) * 64;
  const int lrow = lane & 15, khalf = lane >> 4;
  const int arow = t >> 4, acol = (t & 15) << 2;
  const int brow = t >> 3, bcol = (t & 7) << 3;
  f4 acc[4][4] = {};
  const int nk = K >> 6;
  float4 ra[8]; h8 rb[4];

#define LOAD_TILE(kt) { \
  _Pragma("unroll") for (int i = 0; i < 8; ++i) { \
    const int row = arow + (i << 4); \
    if (bm + row < M) ra[i] = *(const float4*)(A + (size_t)(bm + row) * K + (size_t)(kt) * 64 + acol); \
    else ra[i] = make_float4(0.f, 0.f, 0.f, 0.f); } \
  _Pragma("unroll") for (int i = 0; i < 4; ++i) { \
    const int row = brow + (i << 5); \
    rb[i] = *(const h8*)(Bb + (size_t)(bn + row) * K + (size_t)(kt) * 64 + bcol); } }

#define STORE_TILE() { \
  _Pragma("unroll") for (int i = 0; i < 8; ++i) { \
    const int row = arow + (i << 4); \
    h4v hv = {(_Float16)ra[i].x, (_Float16)ra[i].y, (_Float16)ra[i].z, (_Float16)ra[i].w}; \
    *(h4v*)&As[row][acol] = hv; } \
  _Pragma("unroll") for (int i = 0; i < 4; ++i) { \
    const int row = brow + (i << 5); \
    *(h8*)&Bs[row][bcol] = rb[i]; } }

  LOAD_TILE(0)
  STORE_TILE()
  __syncthreads();
  for (int kt = 0; kt < nk; ++kt) {
    const bool more = (kt + 1 < nk);
    if (more) { LOAD_TILE(kt + 1) }
#pragma unroll
    for (int ks = 0; ks < 2; ++ks) {
      h8 af[4], bf[4];
#pragma unroll
      for (int mi = 0; mi < 4; ++mi) af[mi] = *(const h8*)&As[wr + mi * 16 + lrow][ks * 32 + (khalf << 3)];
#pragma unroll
      for (int ni = 0; ni < 4; ++ni) bf[ni] = *(const h8*)&Bs[wc + ni * 16 + lrow][ks * 32 + (khalf << 3)];
#pragma unroll
      for (int mi = 0; mi < 4; ++mi)
#pragma unroll
        for (int ni = 0; ni < 4; ++ni)
          acc[mi][ni] = __builtin_amdgcn_mfma_f32_16x16x32_f16(af[mi], bf[ni], acc[mi][ni], 0, 0, 0);
    }
    __syncthreads();
    if (more) { STORE_TILE() }
    __syncthreads();
  }
#undef LOAD_TILE
#undef STORE_TILE
  const int crow0 = (lane >> 4) << 2;
  const int ccol = lane & 15;
#pragma unroll
  for (int mi = 0; mi < 4; ++mi) {
#pragma unroll
    for (int r = 0; r < 4; ++r) {
      const int row = bm + wr + mi * 16 + crow0 + r;
      if (row >= M) continue;
#pragma unroll
      for (int ni = 0; ni < 4; ++ni) {
        const int col = bn + wc + ni * 16 + ccol;
        float v = acc[mi][ni][r];
        if (bias) v += bias[col];
        if (RELU) v = fmaxf(v, 0.f);
        if (OUT_HALF) ((__half*)Cv)[(size_t)row * N + col] = __float2half(v);
        else          ((float*)Cv)[(size_t)row * N + col] = v;
      }
    }
  }
}

// standalone GEMM (Wo, W1, W2)
template<bool OUT_HALF, bool RELU>
__global__ __launch_bounds__(256) void mfma_gemm(const float* __restrict__ A,
    const __half* __restrict__ BT, const float* __restrict__ bias, void* __restrict__ Cv,
    int M, int N, int K) {
  __shared__ _Float16 As[128][72];
  __shared__ _Float16 Bs[128][72];
  gemm_body<OUT_HALF, RELU>(As, Bs, A, BT, bias, Cv, M, N, K,
                            blockIdx.y * 128, blockIdx.x * 128, threadIdx.x);
}

// batched: PRb [0,18) + T [18,306) + qkv [306,360)
__global__ __launch_bounds__(256) void gemm_batch(
    const float* __restrict__ peu, const __half* __restrict__ WrT, const float* __restrict__ br,
    float* __restrict__ PRb,
    const __half* __restrict__ BTf1, __half* __restrict__ Tt,
    const float* __restrict__ xb, const __half* __restrict__ BTsq, const float* __restrict__ bqkv,
    float* __restrict__ qkv) {
  __shared__ _Float16 As[128][72];
  __shared__ _Float16 Bs[128][72];
  const int blk = blockIdx.x;
  const int t = threadIdx.x;
  if (blk < 18) {
    gemm_body<false, false>(As, Bs, peu, WrT, br, PRb, NJ, HH, HH,
                            (blk / 6) * 128, (blk % 6) * 128, t);
  } else if (blk < 306) {
    const int i2 = blk - 18;
    const int z = i2 / 72, r = i2 % 72;
    gemm_body<true, false>(As, Bs, peu, BTf1 + (size_t)z * H4 * HH, nullptr,
                           Tt + (size_t)z * NJP * H4, NJ, H4, HH,
                           (r / 24) * 128, (r % 24) * 128, t);
  } else {
    const int i3 = blk - 306;
    gemm_body<false, false>(As, Bs, xb, BTsq, bqkv, qkv, BB * SS, 3 * HH, HH,
                            (i3 / 18) * 128, (i3 % 18) * 128, t);
  }
}

// ================= G[b,n,q,j] = dot(q+v, PRb[j,n,:]) — LDS-staged =================
// grid 128: blk = ((b*8+n)*8 + jt), jt covers 48 j
__global__ __launch_bounds__(256) void g2_kernel(const float* __restrict__ qkv,
    const float* __restrict__ PRb, const float* __restrict__ vv, float* __restrict__ G) {
  __shared__ float Qv[192][100];
  __shared__ float PRs[48][100];
  const int blk = blockIdx.x;
  const int jt = blk & 7, n = (blk >> 3) & 7, b = blk >> 6;
  const int j0 = jt * 48;
  const int t = threadIdx.x;
  for (int i = t; i < 4608; i += 256) {
    const int q = i / 24, c = (i % 24) * 4;
    float4 v = *(const float4*)(qkv + (size_t)(b * 192 + q) * 2304 + n * 96 + c);
    const float4 vb = *(const float4*)(vv + n * 96 + c);
    Qv[q][c] = v.x + vb.x; Qv[q][c + 1] = v.y + vb.y;
    Qv[q][c + 2] = v.z + vb.z; Qv[q][c + 3] = v.w + vb.w;
  }
  for (int i = t; i < 1152; i += 256) {
    const int jr = i / 24, c = (i % 24) * 4;
    const int j = min(j0 + jr, NJ - 1);
    *(f4*)&PRs[jr][c] = *(const f4*)(PRb + (size_t)j * 768 + n * 96 + c);
  }
  __syncthreads();
  const int qt = t >> 4, jt2 = t & 15;
  const int qb0 = qt * 12;
  float acc[12][3] = {};
  for (int dq = 0; dq < 24; ++dq) {
    const f4 p0 = *(const f4*)&PRs[jt2][dq * 4];
    const f4 p1 = *(const f4*)&PRs[jt2 + 16][dq * 4];
    const f4 p2 = *(const f4*)&PRs[jt2 + 32][dq * 4];
#pragma unroll
    for (int qi = 0; qi < 12; ++qi) {
      const f4 qv = *(const f4*)&Qv[qb0 + qi][dq * 4];
      acc[qi][0] += qv.x * p0.x + qv.y * p0.y + qv.z * p0.z + qv.w * p0.w;
      acc[qi][1] += qv.x * p1.x + qv.y * p1.y + qv.z * p1.z + qv.w * p1.w;
      acc[qi][2] += qv.x * p2.x + qv.y * p2.y + qv.z * p2.z + qv.w * p2.w;
    }
  }
  float* Grow = G + (size_t)(b * 8 + n) * 192 * NJP;
#pragma unroll
  for (int qi = 0; qi < 12; ++qi)
#pragma unroll
    for (int ji = 0; ji < 3; ++ji)
      Grow[(size_t)(qb0 + qi) * NJP + j0 + jt2 + 16 * ji] = acc[qi][ji];
}

// ================= pairA: partial w4 logits, inline j, 16-lane groups =================
// grid 4608; chunk = (blk%8)>>1 (XCD-affine 768-channel slice)
__global__ __launch_bounds__(256) void pairA_kernel(const h2* __restrict__ Tt,
    const h8* __restrict__ wf2pG, const h2* __restrict__ bf1pG,
    const int* __restrict__ pos_s, const int* __restrict__ pos_e,
    float* __restrict__ partials) {
  const int blk = blockIdx.x;
  const int chunk = (blk & 7) >> 1;
  const int cbase = chunk * 384;
  const int t = threadIdx.x;
  const int grp = t >> 4, l16 = t & 15;
  const int pbase = (blk >> 3) * 128 + (blk & 1) * 64;
  const h2 zero2 = {(_Float16)0.f, (_Float16)0.f};
  h8 Wr[3][4]; h2 B1[3][4];
#pragma unroll
  for (int s = 0; s < 3; ++s)
#pragma unroll
    for (int v = 0; v < 4; ++v) {
      const int cw = (l16 + 16 * s) * 4 + v;
      Wr[s][v] = wf2pG[cbase + cw];
      B1[s][v] = bf1pG[cbase + cw];
    }
  const h2* Tc = Tt + cbase;
#pragma unroll 2
  for (int i = 0; i < 4; ++i) {
    const int p = pbase + i * 16 + grp;
    const int b = p / 36864;
    const int rem = p - b * 36864;
    const int qq = rem / 192;
    const int kk = rem - qq * 192;
    const int psq = pos_s[b * 192 + qq], peq = pos_e[b * 192 + qq];
    const int psk = pos_s[b * 192 + kk], pek = pos_e[b * 192 + kk];
    const int jx = min(max(psq - psk + 191, 0), NJ - 1);
    const int jy = min(max(psq - pek + 191, 0), NJ - 1);
    const int jz = min(max(peq - psk + 191, 0), NJ - 1);
    const int jw = min(max(peq - pek + 191, 0), NJ - 1);
    const h8* r0 = (const h8*)(Tc + (size_t)jx * 1536);
    const h8* r1 = (const h8*)(Tc + (size_t)(NJP + jy) * 1536);
    const h8* r2 = (const h8*)(Tc + (size_t)(2 * NJP + jz) * 1536);
    const h8* r3 = (const h8*)(Tc + (size_t)(3 * NJP + jw) * 1536);
    h2 c0 = zero2, c1 = zero2, c2 = zero2, c3 = zero2;
#pragma unroll
    for (int s = 0; s < 3; ++s) {
      const int g = l16 + 16 * s;
      union { h8 v; h2 p[4]; } L0, L1, L2, L3;
      L0.v = r0[g]; L1.v = r1[g]; L2.v = r2[g]; L3.v = r3[g];
#pragma unroll
      for (int v = 0; v < 4; ++v) {
        h2 sv = L0.p[v] + L1.p[v];
        sv = sv + L2.p[v];
        sv = sv + L3.p[v];
        sv = sv + B1[s][v];
        sv = __builtin_elementwise_max(sv, zero2);
        union { h8 v; h2 p[4]; } W; W.v = Wr[s][v];
        c0 += sv * W.p[0];
        c1 += sv * W.p[1];
        c2 += sv * W.p[2];
        c3 += sv * W.p[3];
      }
    }
    float a0 = (float)c0.x + (float)c0.y;
    float a1 = (float)c1.x + (float)c1.y;
    float a2 = (float)c2.x + (float)c2.y;
    float a3 = (float)c3.x + (float)c3.y;
#pragma unroll
    for (int off = 8; off > 0; off >>= 1) {
      a0 += __shfl_xor(a0, off, 16);
      a1 += __shfl_xor(a1, off, 16);
      a2 += __shfl_xor(a2, off, 16);
      a3 += __shfl_xor(a3, off, 16);
    }
    if (l16 < 4) {
      const float sel = (l16 == 0) ? a0 : (l16 == 1) ? a1 : (l16 == 2) ? a2 : a3;
      partials[((size_t)chunk * NPAIR + p) * 4 + l16] = sel;
    }
  }
}

// ================= attn2: AC + inline-pairB(w4) + BD + softmax -> P f16 =================
// grid 256: blk = ((b*8+n)*16 + qt), 12 q rows per block
__global__ __launch_bounds__(256) void attn2_kernel(const float* __restrict__ qkv,
    const float* __restrict__ uu, const float* __restrict__ G,
    const float4* __restrict__ parti4, const float* __restrict__ bf2,
    const int* __restrict__ pos_s, const int* __restrict__ pos_e,
    const int* __restrict__ seq_len, const int* __restrict__ lex_num,
    __half* __restrict__ P) {
  __shared__ float Ks[192][100];
  __shared__ float Qs[12][100];
  __shared__ float Gs[12][388];
  __shared__ int poss[192], pose[192];
  const int blk = blockIdx.x;
  const int qt = blk & 15, n = (blk >> 4) & 7, b = blk >> 7;
  const int q0 = qt * 12;
  const int t = threadIdx.x;
  for (int i = t; i < 4608; i += 256) {
    const int k = i / 24, c = (i % 24) * 4;
    *(f4*)&Ks[k][c] = *(const f4*)(qkv + (size_t)(b * 192 + k) * 2304 + 768 + n * 96 + c);
  }
  for (int i = t; i < 288; i += 256) {
    const int qi = i / 24, c = (i % 24) * 4;
    float4 v = *(const float4*)(qkv + (size_t)(b * 192 + q0 + qi) * 2304 + n * 96 + c);
    const float4 ub = *(const float4*)(uu + n * 96 + c);
    Qs[qi][c] = v.x + ub.x; Qs[qi][c + 1] = v.y + ub.y;
    Qs[qi][c + 2] = v.z + ub.z; Qs[qi][c + 3] = v.w + ub.w;
  }
  for (int i = t; i < 1152; i += 256) {
    const int qi = i / 96, c = (i % 96) * 4;
    *(f4*)&Gs[qi][c] = *(const f4*)(G + ((size_t)(b * 8 + n) * 192 + q0 + qi) * NJP + c);
  }
  for (int i = t; i < 192; i += 256) { poss[i] = pos_s[b * 192 + i]; pose[i] = pos_e[b * 192 + i]; }
  __syncthreads();
  const float b20 = bf2[0], b21 = bf2[1], b22 = bf2[2], b23 = bf2[3];
  const int wave = t >> 6, lane = t & 63;
  const int qw = wave * 3;
  float ac[3][3] = {};
  for (int dq = 0; dq < 24; ++dq) {
    const f4 kv0 = *(const f4*)&Ks[lane][dq * 4];
    const f4 kv1 = *(const f4*)&Ks[lane + 64][dq * 4];
    const f4 kv2 = *(const f4*)&Ks[lane + 128][dq * 4];
#pragma unroll
    for (int qi = 0; qi < 3; ++qi) {
      const f4 qv = *(const f4*)&Qs[qw + qi][dq * 4];
      ac[qi][0] += qv.x * kv0.x + qv.y * kv0.y + qv.z * kv0.z + qv.w * kv0.w;
      ac[qi][1] += qv.x * kv1.x + qv.y * kv1.y + qv.z * kv1.z + qv.w * kv1.w;
      ac[qi][2] += qv.x * kv2.x + qv.y * kv2.y + qv.z * kv2.z + qv.w * kv2.w;
    }
  }
  const int vbnd = seq_len[b] + lex_num[b];
#pragma unroll
  for (int qi = 0; qi < 3; ++qi) {
    const int qg = q0 + qw + qi;
    const int psq = poss[qg], peq = pose[qg];
    float v[3];
#pragma unroll
    for (int ki = 0; ki < 3; ++ki) {
      const int k = lane + 64 * ki;
      const int psk = poss[k], pek = pose[k];
      const int jss = min(max(psq - psk + 191, 0), NJ - 1);
      const int jse = min(max(psq - pek + 191, 0), NJ - 1);
      const int jes = min(max(peq - psk + 191, 0), NJ - 1);
      const int jee = min(max(peq - pek + 191, 0), NJ - 1);
      // inline pairB: combine 4 chunk partials -> w4 softmax
      const int pidx = b * 36864 + qg * 192 + k;
      const float4 s0 = parti4[pidx];
      const float4 s1 = parti4[NPAIR + pidx];
      const float4 s2 = parti4[2 * NPAIR + pidx];
      const float4 s3 = parti4[3 * NPAIR + pidx];
      const float l0 = s0.x + s1.x + s2.x + s3.x + b20;
      const float l1 = s0.y + s1.y + s2.y + s3.y + b21;
      const float l2 = s0.z + s1.z + s2.z + s3.z + b22;
      const float l3 = s0.w + s1.w + s2.w + s3.w + b23;
      const float lm = fmaxf(fmaxf(l0, l1), fmaxf(l2, l3));
      const float e0 = __expf(l0 - lm), e1 = __expf(l1 - lm);
      const float e2 = __expf(l2 - lm), e3 = __expf(l3 - lm);
      const float winv = 1.f / (e0 + e1 + e2 + e3);
      const float bd = (e0 * Gs[qw + qi][jss] + e1 * Gs[qw + qi][jse]
                      + e2 * Gs[qw + qi][jes] + e3 * Gs[qw + qi][jee]) * winv;
      const float a = (ac[qi][ki] + bd) * ATT_SCALE;
      v[ki] = (k < vbnd) ? a : -1e15f;
    }
    float mx = fmaxf(fmaxf(v[0], v[1]), v[2]);
#pragma unroll
    for (int off = 1; off < 64; off <<= 1) mx = fmaxf(mx, __shfl_xor(mx, off, 64));
    const float e0 = __expf(v[0] - mx), e1 = __expf(v[1] - mx), e2 = __expf(v[2] - mx);
    float sm = e0 + e1 + e2;
#pragma unroll
    for (int off = 1; off < 64; off <<= 1) sm += __shfl_xor(sm, off, 64);
    const float inv = 1.f / sm;
    __half* pr = P + ((size_t)(b * 8 + n) * 192 + qg) * 192;
    pr[lane] = __float2half(e0 * inv);
    pr[lane + 64] = __float2half(e1 * inv);
    pr[lane + 128] = __float2half(e2 * inv);
  }
}

// ================= ctx2: ctx = P @ V =================
// grid 64: blk = ((b*8+n)*4 + qt), 48 q rows per block
__global__ __launch_bounds__(256) void ctx2_kernel(const __half* __restrict__ P,
    const float* __restrict__ qkv, float* __restrict__ ctx) {
  __shared__ float Vs[192][100];
  __shared__ float Ps[48][196];
  const int blk = blockIdx.x;
  const int qt = blk & 3, n = (blk >> 2) & 7, b = blk >> 5;
  const int q0 = qt * 48;
  const int t = threadIdx.x;
  for (int i = t; i < 4608; i += 256) {
    const int k = i / 24, c = (i % 24) * 4;
    *(f4*)&Vs[k][c] = *(const f4*)(qkv + (size_t)(b * 192 + k) * 2304 + 1536 + n * 96 + c);
  }
  const __half* Pb = P + ((size_t)(b * 8 + n) * 192 + q0) * 192;
  for (int i = t; i < 4608; i += 256) {
    const int qi = i / 96, c = (i % 96) * 2;
    const h2 pv = *(const h2*)(Pb + (size_t)qi * 192 + c);
    Ps[qi][c] = (float)pv.x; Ps[qi][c + 1] = (float)pv.y;
  }
  __syncthreads();
  const int qt2 = t >> 5, dt = t & 31;
  const int qb0 = qt2 * 6;
  float acc[6][3] = {};
  for (int k4 = 0; k4 < 48; ++k4) {
    const int k = k4 * 4;
    f4 pq[6];
#pragma unroll
    for (int qi = 0; qi < 6; ++qi) pq[qi] = *(const f4*)&Ps[qb0 + qi][k];
#pragma unroll
    for (int kk = 0; kk < 4; ++kk) {
      const float v0 = Vs[k + kk][dt];
      const float v1 = Vs[k + kk][dt + 32];
      const float v2 = Vs[k + kk][dt + 64];
#pragma unroll
      for (int qi = 0; qi < 6; ++qi) {
        const float pv = pq[qi][kk];
        acc[qi][0] += pv * v0; acc[qi][1] += pv * v1; acc[qi][2] += pv * v2;
      }
    }
  }
#pragma unroll
  for (int qi = 0; qi < 6; ++qi) {
    float* cr = ctx + (size_t)(b * 192 + q0 + qb0 + qi) * 768 + n * 96;
    cr[dt] = acc[qi][0]; cr[dt + 32] = acc[qi][1]; cr[dt + 64] = acc[qi][2];
  }
}

// ================= out = LayerNorm(xin + dres) * g + b =================
__global__ __launch_bounds__(256) void ln_kernel(const float* __restrict__ xin,
    const float* __restrict__ dres, const float* __restrict__ g,
    const float* __restrict__ bta, float* __restrict__ out) {
  const int row = blockIdx.x;
  const int t = threadIdx.x;
  __shared__ float red[256];
  const size_t base = (size_t)row * HH;
  const float v0 = xin[base + t] + dres[base + t];
  const float v1 = xin[base + 256 + t] + dres[base + 256 + t];
  const float v2 = xin[base + 512 + t] + dres[base + 512 + t];
  red[t] = v0 + v1 + v2; __syncthreads();
  for (int s = 128; s > 0; s >>= 1) { if (t < s) red[t] += red[t + s]; __syncthreads(); }
  const float mean = red[0] * (1.f / 768.f); __syncthreads();
  red[t] = v0 * v0 + v1 * v1 + v2 * v2; __syncthreads();
  for (int s = 128; s > 0; s >>= 1) { if (t < s) red[t] += red[t + s]; __syncthreads(); }
  const float var = red[0] * (1.f / 768.f) - mean * mean;
  const float rstd = rsqrtf(var + 1e-5f);
  out[base + t]       = (v0 - mean) * rstd * g[t]       + bta[t];
  out[base + 256 + t] = (v1 - mean) * rstd * g[256 + t] + bta[256 + t];
  out[base + 512 + t] = (v2 - mean) * rstd * g[512 + t] + bta[512 + t];
}

extern "C" void kernel_launch(void* const* d_in, const int* in_sizes, int n_in,
                              void* d_out, int out_size, void* d_ws, size_t ws_size,
                              hipStream_t stream) {
  const float* we      = (const float*)d_in[0];
  const float* be      = (const float*)d_in[1];
  const int*   seq_len = (const int*)d_in[2];
  const int*   lex_num = (const int*)d_in[3];
  const int*   pos_s   = (const int*)d_in[4];
  const int*   pos_e   = (const int*)d_in[5];
  const float* pe      = (const float*)d_in[6];
  const float* Wf1     = (const float*)d_in[7];
  const float* bf1     = (const float*)d_in[8];
  const float* Wf2     = (const float*)d_in[9];
  const float* bf2     = (const float*)d_in[10];
  const float* Wq = (const float*)d_in[11]; const float* bq = (const float*)d_in[12];
  const float* Wk = (const float*)d_in[13]; const float* bk = (const float*)d_in[14];
  const float* Wv = (const float*)d_in[15]; const float* bv = (const float*)d_in[16];
  const float* Wr = (const float*)d_in[17]; const float* br = (const float*)d_in[18];
  const float* uu = (const float*)d_in[19]; const float* vv = (const float*)d_in[20];
  const float* Wo = (const float*)d_in[21]; const float* bo = (const float*)d_in[22];
  const float* g1 = (const float*)d_in[23]; const float* be1 = (const float*)d_in[24];
  const float* W1 = (const float*)d_in[25]; const float* b1 = (const float*)d_in[26];
  const float* W2 = (const float*)d_in[27]; const float* b2 = (const float*)d_in[28];
  const float* g2 = (const float*)d_in[29]; const float* be2 = (const float*)d_in[30];

  // workspace layout (bytes, 16B aligned)
  char* ws = (char*)d_ws;
  float*  xb    = (float*)(ws + 0);          // [384,768]
  float*  qkv   = (float*)(ws + 1179648);    // [384,2304]
  float*  PRb   = (float*)(ws + 4718592);    // [383,768]
  __half* Tt    = (__half*)(ws + 5898240);   // [4,384,3072] f16
  __half* BTf1  = (__half*)(ws + 15335424);  // [4,3072,768] f16, dead after gemm_batch:
  float*  G     = (float*)(ws + 15335424);   //   [2,8,192,384]
  float*  parti = (float*)(ws + 20054016);   //   [4,73728,4]
  __half* P     = (__half*)(ws + 25952256);  //   [2,8,192,192] f16
  float*  ctx   = (float*)(ws + 27131904);   //   [384,768]
  float*  ao    = (float*)(ws + 28311552);   //   [384,768]
  float*  x1    = (float*)(ws + 29491200);   //   [384,768]
  float*  ff    = (float*)(ws + 30670848);   //   [384,768]
  float*  fo    = (float*)(ws + 31850496);   //   [384,768] (ends 33030144)
  __half* BTsq  = (__half*)(ws + 34209792);  // [7,768,768] f16: Wq,Wk,Wv,Wo,W1,W2,Wr
  h2*     wf2pG = (h2*)(ws + 42467328);
  h2*     bf1pG = (h2*)(ws + 42491904);
  float*  bqkv  = (float*)(ws + 42498048);   // [2304]
  float*  out   = (float*)d_out;

  const float* peu = pe + (size_t)JOFF * HH;
  const size_t SQ = (size_t)HH * HH;
  __half* WoT = BTsq + 3 * SQ; __half* W1T = BTsq + 4 * SQ;
  __half* W2T = BTsq + 5 * SQ; __half* WrT = BTsq + 6 * SQ;

  // 1. prep: add + pack + trans7 + trans_cvt
  prep_kernel<<<13537, 256, 0, stream>>>((const float4*)we, (const float4*)be, (float4*)xb,
      Wf2, bf1, bq, bk, bv, wf2pG, bf1pG, bqkv,
      Wq, Wk, Wv, Wo, W1, W2, Wr, BTsq, Wf1, BTf1);
  // 2. batched GEMM: PRb + 4xT + qkv
  gemm_batch<<<360, 256, 0, stream>>>(peu, WrT, br, PRb, BTf1, Tt, xb, BTsq, bqkv, qkv);
  // 3. G precompute
  g2_kernel<<<128, 256, 0, stream>>>(qkv, PRb, vv, G);
  // 4. pairA (inline j)
  pairA_kernel<<<4608, 256, 0, stream>>>((const h2*)Tt, (const h8*)wf2pG, bf1pG,
      pos_s, pos_e, parti);
  // 5. attn2 (inline pairB)
  attn2_kernel<<<256, 256, 0, stream>>>(qkv, uu, G, (const float4*)parti, bf2,
      pos_s, pos_e, seq_len, lex_num, P);
  // 6. ctx2
  ctx2_kernel<<<64, 256, 0, stream>>>(P, qkv, ctx);
  // 7-11. out-proj, LN1, FFN, LN2
  mfma_gemm<false, false><<<dim3(6, 3), 256, 0, stream>>>(ctx, WoT, bo, ao, BB * SS, HH, HH);
  ln_kernel<<<BB * SS, 256, 0, stream>>>(xb, ao, g1, be1, x1);
  mfma_gemm<false, true><<<dim3(6, 3), 256, 0, stream>>>(x1, W1T, b1, ff, BB * SS, HH, HH);
  mfma_gemm<false, false><<<dim3(6, 3), 256, 0, stream>>>(ff, W2T, b2, fo, BB * SS, HH, HH);
  ln_kernel<<<BB * SS, 256, 0, stream>>>(x1, fo, g2, be2, out);
}

// Round 9
// 344.272 us; speedup vs baseline: 2.8889x; 1.1786x over previous
//
#include <hip/hip_runtime.h>
#include <hip/hip_bf16.h>
#include <hip/hip_fp16.h>
#include <cstdint>

#define BB 2
#define SS 192
#define HH 768
#define NHH 8
#define DHH 96
#define H4 3072
#define NJ 383          // used pe rows: idx in [321, 703]
#define NJP 384
#define JOFF 321
#define NPAIR 73728     // 2*192*192
#define ATT_SCALE 0.10206207261596575f   // 1/sqrt(96)

typedef _Float16 h2 __attribute__((ext_vector_type(2)));
typedef _Float16 h4v __attribute__((ext_vector_type(4)));
typedef _Float16 h8 __attribute__((ext_vector_type(8)));
typedef float f4 __attribute__((ext_vector_type(4)));

// ================= prep: add + pack + trans7 + trans_cvt in one launch =================
__global__ __launch_bounds__(256) void prep_kernel(
    const float4* __restrict__ we, const float4* __restrict__ be, float4* __restrict__ xb,
    const float* __restrict__ wf2, const float* __restrict__ bf1,
    const float* __restrict__ bq, const float* __restrict__ bk, const float* __restrict__ bv,
    h2* __restrict__ wf2pG, h2* __restrict__ bf1pG, float* __restrict__ bqkv,
    const float* __restrict__ s0, const float* __restrict__ s1, const float* __restrict__ s2,
    const float* __restrict__ s3, const float* __restrict__ s4, const float* __restrict__ s5,
    const float* __restrict__ s6, __half* __restrict__ BTsq,
    const float* __restrict__ Wf1, __half* __restrict__ BTf1) {
  __shared__ float tile[32][33];
  const int blk = blockIdx.x;
  const int t = threadIdx.x;
  if (blk < 288) {
    const int i = blk * 256 + t;
    float4 va = we[i], vb = be[i];
    xb[i] = make_float4(va.x + vb.x, va.y + vb.y, va.z + vb.z, va.w + vb.w);
  } else if (blk == 288) {
    for (int i = t; i < 6144; i += 256) {
      const int cw = i >> 2, f = i & 3;
      h2 v = {(_Float16)wf2[8 * cw + f], (_Float16)wf2[8 * cw + 4 + f]};
      wf2pG[i] = v;
    }
    for (int i = t; i < 1536; i += 256) {
      h2 v = {(_Float16)bf1[2 * i], (_Float16)bf1[2 * i + 1]};
      bf1pG[i] = v;
    }
    for (int i = t; i < 768; i += 256) {
      bqkv[i] = bq[i]; bqkv[768 + i] = bk[i]; bqkv[1536 + i] = bv[i];
    }
  } else if (blk < 4321) {
    const int i7 = blk - 289;
    const int z = i7 / 576, rem = i7 % 576;
    const int y = (rem / 24) * 32, x = (rem % 24) * 32;
    const float* src;
    switch (z) {
      case 0: src = s0; break; case 1: src = s1; break; case 2: src = s2; break;
      case 3: src = s3; break; case 4: src = s4; break; case 5: src = s5; break;
      default: src = s6; break;
    }
    __half* dst = BTsq + (size_t)z * HH * HH;
    const int tx = t & 31, ty = t >> 5;
#pragma unroll
    for (int i = 0; i < 4; ++i)
      tile[ty + 8 * i][tx] = src[(size_t)(y + ty + 8 * i) * HH + x + tx];
    __syncthreads();
#pragma unroll
    for (int i = 0; i < 4; ++i)
      dst[(size_t)(x + ty + 8 * i) * HH + y + tx] = __float2half(tile[tx][ty + 8 * i]);
  } else {
    const int ic = blk - 4321;
    const int z = ic / 2304, rem = ic % 2304;
    const int y = (rem / 96) * 32, x = (rem % 96) * 32;
    const float* src = Wf1 + (size_t)z * HH * H4;
    __half* dst = BTf1 + (size_t)z * HH * H4;
    const int tx = t & 31, ty = t >> 5;
#pragma unroll
    for (int i = 0; i < 4; ++i)
      tile[ty + 8 * i][tx] = src[(size_t)(y + ty + 8 * i) * H4 + x + tx];
    __syncthreads();
#pragma unroll
    for (int i = 0; i < 4; ++i)
      dst[(size_t)(x + ty + 8 * i) * HH + y + tx] = __float2half(tile[tx][ty + 8 * i]);
  }
}

// ================= MFMA GEMM body: 8 waves (512 thr), 128x128 tile, wave=64x32 =========
template<bool OUT_HALF, bool RELU>
__device__ __forceinline__ void gemm_body(_Float16 (*As)[72], _Float16 (*Bs)[72],
    const float* __restrict__ A, const __half* __restrict__ Bb, const float* __restrict__ bias,
    void* __restrict__ Cv, int M, int N, int K, int bm, int bn, int t) {
  const int wave = t >> 6, lane = t & 63;
  const int wr = (wave >> 2) * 64, wc = (wave & 3) * 32;
  const int lrow = lane & 15, khalf = lane >> 4;
  const int arow = t >> 4, acol = (t & 15) << 2;   // arow 0..31; rows arow+32i, i<4
  const int brow = t >> 3, bcol = (t & 7) << 3;    // brow 0..63; rows brow+64i, i<2
  f4 acc[4][2] = {};
  const int nk = K >> 6;
  float4 ra[4]; h8 rb[2];

#define LOAD_TILE(kt) { \
  _Pragma("unroll") for (int i = 0; i < 4; ++i) { \
    const int row = arow + (i << 5); \
    if (bm + row < M) ra[i] = *(const float4*)(A + (size_t)(bm + row) * K + (size_t)(kt) * 64 + acol); \
    else ra[i] = make_float4(0.f, 0.f, 0.f, 0.f); } \
  _Pragma("unroll") for (int i = 0; i < 2; ++i) { \
    const int row = brow + (i << 6); \
    rb[i] = *(const h8*)(Bb + (size_t)(bn + row) * K + (size_t)(kt) * 64 + bcol); } }

#define STORE_TILE() { \
  _Pragma("unroll") for (int i = 0; i < 4; ++i) { \
    const int row = arow + (i << 5); \
    h4v hv = {(_Float16)ra[i].x, (_Float16)ra[i].y, (_Float16)ra[i].z, (_Float16)ra[i].w}; \
    *(h4v*)&As[row][acol] = hv; } \
  _Pragma("unroll") for (int i = 0; i < 2; ++i) { \
    const int row = brow + (i << 6); \
    *(h8*)&Bs[row][bcol] = rb[i]; } }

  LOAD_TILE(0)
  STORE_TILE()
  __syncthreads();
  for (int kt = 0; kt < nk; ++kt) {
    const bool more = (kt + 1 < nk);
    if (more) { LOAD_TILE(kt + 1) }
#pragma unroll
    for (int ks = 0; ks < 2; ++ks) {
      h8 af[4], bf[2];
#pragma unroll
      for (int mi = 0; mi < 4; ++mi) af[mi] = *(const h8*)&As[wr + mi * 16 + lrow][ks * 32 + (khalf << 3)];
#pragma unroll
      for (int ni = 0; ni < 2; ++ni) bf[ni] = *(const h8*)&Bs[wc + ni * 16 + lrow][ks * 32 + (khalf << 3)];
#pragma unroll
      for (int mi = 0; mi < 4; ++mi)
#pragma unroll
        for (int ni = 0; ni < 2; ++ni)
          acc[mi][ni] = __builtin_amdgcn_mfma_f32_16x16x32_f16(af[mi], bf[ni], acc[mi][ni], 0, 0, 0);
    }
    __syncthreads();
    if (more) { STORE_TILE() }
    __syncthreads();
  }
#undef LOAD_TILE
#undef STORE_TILE
  const int crow0 = (lane >> 4) << 2;
  const int ccol = lane & 15;
#pragma unroll
  for (int mi = 0; mi < 4; ++mi) {
#pragma unroll
    for (int r = 0; r < 4; ++r) {
      const int row = bm + wr + mi * 16 + crow0 + r;
      if (row >= M) continue;
#pragma unroll
      for (int ni = 0; ni < 2; ++ni) {
        const int col = bn + wc + ni * 16 + ccol;
        float v = acc[mi][ni][r];
        if (bias) v += bias[col];
        if (RELU) v = fmaxf(v, 0.f);
        if (OUT_HALF) ((__half*)Cv)[(size_t)row * N + col] = __float2half(v);
        else          ((float*)Cv)[(size_t)row * N + col] = v;
      }
    }
  }
}

// standalone GEMM (Wo, W1, W2)
template<bool OUT_HALF, bool RELU>
__global__ __launch_bounds__(512) void mfma_gemm(const float* __restrict__ A,
    const __half* __restrict__ BT, const float* __restrict__ bias, void* __restrict__ Cv,
    int M, int N, int K) {
  __shared__ _Float16 As[128][72];
  __shared__ _Float16 Bs[128][72];
  gemm_body<OUT_HALF, RELU>(As, Bs, A, BT, bias, Cv, M, N, K,
                            blockIdx.y * 128, blockIdx.x * 128, threadIdx.x);
}

// batched: PRb [0,18) + T [18,306) + qkv [306,360)
__global__ __launch_bounds__(512) void gemm_batch(
    const float* __restrict__ peu, const __half* __restrict__ WrT, const float* __restrict__ br,
    float* __restrict__ PRb,
    const __half* __restrict__ BTf1, __half* __restrict__ Tt,
    const float* __restrict__ xb, const __half* __restrict__ BTsq, const float* __restrict__ bqkv,
    float* __restrict__ qkv) {
  __shared__ _Float16 As[128][72];
  __shared__ _Float16 Bs[128][72];
  const int blk = blockIdx.x;
  const int t = threadIdx.x;
  if (blk < 18) {
    gemm_body<false, false>(As, Bs, peu, WrT, br, PRb, NJ, HH, HH,
                            (blk / 6) * 128, (blk % 6) * 128, t);
  } else if (blk < 306) {
    const int i2 = blk - 18;
    const int z = i2 / 72, r = i2 % 72;
    gemm_body<true, false>(As, Bs, peu, BTf1 + (size_t)z * H4 * HH, nullptr,
                           Tt + (size_t)z * NJP * H4, NJ, H4, HH,
                           (r / 24) * 128, (r % 24) * 128, t);
  } else {
    const int i3 = blk - 306;
    gemm_body<false, false>(As, Bs, xb, BTsq, bqkv, qkv, BB * SS, 3 * HH, HH,
                            (i3 / 18) * 128, (i3 % 18) * 128, t);
  }
}

// ================= G[b,n,q,j] = dot(q+v, PRb[j,n,:]) — LDS-staged =================
// grid 128: blk = ((b*8+n)*8 + jt), jt covers 48 j
__global__ __launch_bounds__(256) void g2_kernel(const float* __restrict__ qkv,
    const float* __restrict__ PRb, const float* __restrict__ vv, float* __restrict__ G) {
  __shared__ float Qv[192][100];
  __shared__ float PRs[48][100];
  const int blk = blockIdx.x;
  const int jt = blk & 7, n = (blk >> 3) & 7, b = blk >> 6;
  const int j0 = jt * 48;
  const int t = threadIdx.x;
  for (int i = t; i < 4608; i += 256) {
    const int q = i / 24, c = (i % 24) * 4;
    float4 v = *(const float4*)(qkv + (size_t)(b * 192 + q) * 2304 + n * 96 + c);
    const float4 vb = *(const float4*)(vv + n * 96 + c);
    Qv[q][c] = v.x + vb.x; Qv[q][c + 1] = v.y + vb.y;
    Qv[q][c + 2] = v.z + vb.z; Qv[q][c + 3] = v.w + vb.w;
  }
  for (int i = t; i < 1152; i += 256) {
    const int jr = i / 24, c = (i % 24) * 4;
    const int j = min(j0 + jr, NJ - 1);
    *(f4*)&PRs[jr][c] = *(const f4*)(PRb + (size_t)j * 768 + n * 96 + c);
  }
  __syncthreads();
  const int qt = t >> 4, jt2 = t & 15;
  const int qb0 = qt * 12;
  float acc[12][3] = {};
  for (int dq = 0; dq < 24; ++dq) {
    const f4 p0 = *(const f4*)&PRs[jt2][dq * 4];
    const f4 p1 = *(const f4*)&PRs[jt2 + 16][dq * 4];
    const f4 p2 = *(const f4*)&PRs[jt2 + 32][dq * 4];
#pragma unroll
    for (int qi = 0; qi < 12; ++qi) {
      const f4 qv = *(const f4*)&Qv[qb0 + qi][dq * 4];
      acc[qi][0] += qv.x * p0.x + qv.y * p0.y + qv.z * p0.z + qv.w * p0.w;
      acc[qi][1] += qv.x * p1.x + qv.y * p1.y + qv.z * p1.z + qv.w * p1.w;
      acc[qi][2] += qv.x * p2.x + qv.y * p2.y + qv.z * p2.z + qv.w * p2.w;
    }
  }
  float* Grow = G + (size_t)(b * 8 + n) * 192 * NJP;
#pragma unroll
  for (int qi = 0; qi < 12; ++qi)
#pragma unroll
    for (int ji = 0; ji < 3; ++ji)
      Grow[(size_t)(qb0 + qi) * NJP + j0 + jt2 + 16 * ji] = acc[qi][ji];
}

// ================= pairA: partial w4 logits, inline j, 16-lane groups =================
__global__ __launch_bounds__(256) void pairA_kernel(const h2* __restrict__ Tt,
    const h8* __restrict__ wf2pG, const h2* __restrict__ bf1pG,
    const int* __restrict__ pos_s, const int* __restrict__ pos_e,
    float* __restrict__ partials) {
  const int blk = blockIdx.x;
  const int chunk = (blk & 7) >> 1;
  const int cbase = chunk * 384;
  const int t = threadIdx.x;
  const int grp = t >> 4, l16 = t & 15;
  const int pbase = (blk >> 3) * 128 + (blk & 1) * 64;
  const h2 zero2 = {(_Float16)0.f, (_Float16)0.f};
  h8 Wr[3][4]; h2 B1[3][4];
#pragma unroll
  for (int s = 0; s < 3; ++s)
#pragma unroll
    for (int v = 0; v < 4; ++v) {
      const int cw = (l16 + 16 * s) * 4 + v;
      Wr[s][v] = wf2pG[cbase + cw];
      B1[s][v] = bf1pG[cbase + cw];
    }
  const h2* Tc = Tt + cbase;
#pragma unroll 2
  for (int i = 0; i < 4; ++i) {
    const int p = pbase + i * 16 + grp;
    const int b = p / 36864;
    const int rem = p - b * 36864;
    const int qq = rem / 192;
    const int kk = rem - qq * 192;
    const int psq = pos_s[b * 192 + qq], peq = pos_e[b * 192 + qq];
    const int psk = pos_s[b * 192 + kk], pek = pos_e[b * 192 + kk];
    const int jx = min(max(psq - psk + 191, 0), NJ - 1);
    const int jy = min(max(psq - pek + 191, 0), NJ - 1);
    const int jz = min(max(peq - psk + 191, 0), NJ - 1);
    const int jw = min(max(peq - pek + 191, 0), NJ - 1);
    const h8* r0 = (const h8*)(Tc + (size_t)jx * 1536);
    const h8* r1 = (const h8*)(Tc + (size_t)(NJP + jy) * 1536);
    const h8* r2 = (const h8*)(Tc + (size_t)(2 * NJP + jz) * 1536);
    const h8* r3 = (const h8*)(Tc + (size_t)(3 * NJP + jw) * 1536);
    h2 c0 = zero2, c1 = zero2, c2 = zero2, c3 = zero2;
#pragma unroll
    for (int s = 0; s < 3; ++s) {
      const int g = l16 + 16 * s;
      union { h8 v; h2 p[4]; } L0, L1, L2, L3;
      L0.v = r0[g]; L1.v = r1[g]; L2.v = r2[g]; L3.v = r3[g];
#pragma unroll
      for (int v = 0; v < 4; ++v) {
        h2 sv = L0.p[v] + L1.p[v];
        sv = sv + L2.p[v];
        sv = sv + L3.p[v];
        sv = sv + B1[s][v];
        sv = __builtin_elementwise_max(sv, zero2);
        union { h8 v; h2 p[4]; } W; W.v = Wr[s][v];
        c0 += sv * W.p[0];
        c1 += sv * W.p[1];
        c2 += sv * W.p[2];
        c3 += sv * W.p[3];
      }
    }
    float a0 = (float)c0.x + (float)c0.y;
    float a1 = (float)c1.x + (float)c1.y;
    float a2 = (float)c2.x + (float)c2.y;
    float a3 = (float)c3.x + (float)c3.y;
#pragma unroll
    for (int off = 8; off > 0; off >>= 1) {
      a0 += __shfl_xor(a0, off, 16);
      a1 += __shfl_xor(a1, off, 16);
      a2 += __shfl_xor(a2, off, 16);
      a3 += __shfl_xor(a3, off, 16);
    }
    if (l16 < 4) {
      const float sel = (l16 == 0) ? a0 : (l16 == 1) ? a1 : (l16 == 2) ? a2 : a3;
      partials[((size_t)chunk * NPAIR + p) * 4 + l16] = sel;
    }
  }
}

// ================= attn3: AC(f16 K) + inline-pairB + BD + softmax -> P f16 ============
// grid 512: blk = ((b*8+n)*32 + qt), 6 q rows/block, 1 wave per q row (384 thr)
__global__ __launch_bounds__(384) void attn3_kernel(const float* __restrict__ qkv,
    const float* __restrict__ uu, const float* __restrict__ G,
    const float4* __restrict__ parti4, const float* __restrict__ bf2,
    const int* __restrict__ pos_s, const int* __restrict__ pos_e,
    const int* __restrict__ seq_len, const int* __restrict__ lex_num,
    __half* __restrict__ P) {
  __shared__ _Float16 Kh[192][100];
  __shared__ float Qs[6][100];
  __shared__ float Gs[6][388];
  __shared__ int poss[192], pose[192];
  const int blk = blockIdx.x;
  const int qt = blk & 31, n = (blk >> 5) & 7, b = blk >> 8;
  const int q0 = qt * 6;
  const int t = threadIdx.x;
  for (int i = t; i < 4608; i += 384) {
    const int k = i / 24, c = (i % 24) * 4;
    const float4 v = *(const float4*)(qkv + (size_t)(b * 192 + k) * 2304 + 768 + n * 96 + c);
    h4v hv = {(_Float16)v.x, (_Float16)v.y, (_Float16)v.z, (_Float16)v.w};
    *(h4v*)&Kh[k][c] = hv;
  }
  if (t < 144) {
    const int qi = t / 24, c = (t % 24) * 4;
    float4 v = *(const float4*)(qkv + (size_t)(b * 192 + q0 + qi) * 2304 + n * 96 + c);
    const float4 ub = *(const float4*)(uu + n * 96 + c);
    Qs[qi][c] = v.x + ub.x; Qs[qi][c + 1] = v.y + ub.y;
    Qs[qi][c + 2] = v.z + ub.z; Qs[qi][c + 3] = v.w + ub.w;
  }
  for (int i = t; i < 576; i += 384) {
    const int qi = i / 96, c = (i % 96) * 4;
    *(f4*)&Gs[qi][c] = *(const f4*)(G + ((size_t)(b * 8 + n) * 192 + q0 + qi) * NJP + c);
  }
  for (int i = t; i < 192; i += 384) { poss[i] = pos_s[b * 192 + i]; pose[i] = pos_e[b * 192 + i]; }
  __syncthreads();
  const float b20 = bf2[0], b21 = bf2[1], b22 = bf2[2], b23 = bf2[3];
  const int wave = t >> 6, lane = t & 63;   // wave 0..5 = local q row
  float ac0 = 0.f, ac1 = 0.f, ac2 = 0.f;
  for (int dq = 0; dq < 24; ++dq) {
    const f4 qv = *(const f4*)&Qs[wave][dq * 4];
    const h4v k0 = *(const h4v*)&Kh[lane][dq * 4];
    const h4v k1 = *(const h4v*)&Kh[lane + 64][dq * 4];
    const h4v k2 = *(const h4v*)&Kh[lane + 128][dq * 4];
    ac0 += qv.x * (float)k0.x + qv.y * (float)k0.y + qv.z * (float)k0.z + qv.w * (float)k0.w;
    ac1 += qv.x * (float)k1.x + qv.y * (float)k1.y + qv.z * (float)k1.z + qv.w * (float)k1.w;
    ac2 += qv.x * (float)k2.x + qv.y * (float)k2.y + qv.z * (float)k2.z + qv.w * (float)k2.w;
  }
  const int vbnd = seq_len[b] + lex_num[b];
  const int qg = q0 + wave;
  const int psq = poss[qg], peq = pose[qg];
  float v[3];
  const float acv[3] = {ac0, ac1, ac2};
#pragma unroll
  for (int ki = 0; ki < 3; ++ki) {
    const int k = lane + 64 * ki;
    const int psk = poss[k], pek = pose[k];
    const int jss = min(max(psq - psk + 191, 0), NJ - 1);
    const int jse = min(max(psq - pek + 191, 0), NJ - 1);
    const int jes = min(max(peq - psk + 191, 0), NJ - 1);
    const int jee = min(max(peq - pek + 191, 0), NJ - 1);
    const int pidx = b * 36864 + qg * 192 + k;
    const float4 s0 = parti4[pidx];
    const float4 s1 = parti4[NPAIR + pidx];
    const float4 s2 = parti4[2 * NPAIR + pidx];
    const float4 s3 = parti4[3 * NPAIR + pidx];
    const float l0 = s0.x + s1.x + s2.x + s3.x + b20;
    const float l1 = s0.y + s1.y + s2.y + s3.y + b21;
    const float l2 = s0.z + s1.z + s2.z + s3.z + b22;
    const float l3 = s0.w + s1.w + s2.w + s3.w + b23;
    const float lm = fmaxf(fmaxf(l0, l1), fmaxf(l2, l3));
    const float e0 = __expf(l0 - lm), e1 = __expf(l1 - lm);
    const float e2 = __expf(l2 - lm), e3 = __expf(l3 - lm);
    const float winv = 1.f / (e0 + e1 + e2 + e3);
    const float bd = (e0 * Gs[wave][jss] + e1 * Gs[wave][jse]
                    + e2 * Gs[wave][jes] + e3 * Gs[wave][jee]) * winv;
    const float a = (acv[ki] + bd) * ATT_SCALE;
    v[ki] = (k < vbnd) ? a : -1e15f;
  }
  float mx = fmaxf(fmaxf(v[0], v[1]), v[2]);
#pragma unroll
  for (int off = 1; off < 64; off <<= 1) mx = fmaxf(mx, __shfl_xor(mx, off, 64));
  const float e0 = __expf(v[0] - mx), e1 = __expf(v[1] - mx), e2 = __expf(v[2] - mx);
  float sm = e0 + e1 + e2;
#pragma unroll
  for (int off = 1; off < 64; off <<= 1) sm += __shfl_xor(sm, off, 64);
  const float inv = 1.f / sm;
  __half* pr = P + ((size_t)(b * 8 + n) * 192 + qg) * 192;
  pr[lane] = __float2half(e0 * inv);
  pr[lane + 64] = __float2half(e1 * inv);
  pr[lane + 128] = __float2half(e2 * inv);
}

// ================= ctx3: ctx = P @ V (f16 V staged, P broadcast) =================
// grid 256: blk = ((b*8+n)*16 + qt), 12 q rows, 384 thr: d=t%96, qg=t/96 owns 3 q
__global__ __launch_bounds__(384) void ctx3_kernel(const __half* __restrict__ P,
    const float* __restrict__ qkv, float* __restrict__ ctx) {
  __shared__ _Float16 Vh[192][100];
  __shared__ float Ps[12][192];
  const int blk = blockIdx.x;
  const int qt = blk & 15, n = (blk >> 4) & 7, b = blk >> 7;
  const int q0 = qt * 12;
  const int t = threadIdx.x;
  for (int i = t; i < 4608; i += 384) {
    const int k = i / 24, c = (i % 24) * 4;
    const float4 v = *(const float4*)(qkv + (size_t)(b * 192 + k) * 2304 + 1536 + n * 96 + c);
    h4v hv = {(_Float16)v.x, (_Float16)v.y, (_Float16)v.z, (_Float16)v.w};
    *(h4v*)&Vh[k][c] = hv;
  }
  const __half* Pb = P + ((size_t)(b * 8 + n) * 192 + q0) * 192;
  for (int i = t; i < 1152; i += 384) {
    const int qi = i / 96, c = (i % 96) * 2;
    const h2 pv = *(const h2*)(Pb + (size_t)qi * 192 + c);
    Ps[qi][c] = (float)pv.x; Ps[qi][c + 1] = (float)pv.y;
  }
  __syncthreads();
  const int d = t % 96, qg = t / 96;   // qg 0..3
  const int qb0 = qg * 3;
  float a0 = 0.f, a1 = 0.f, a2 = 0.f;
#pragma unroll 4
  for (int k = 0; k < 192; ++k) {
    const float vv = (float)Vh[k][d];
    a0 += Ps[qb0 + 0][k] * vv;
    a1 += Ps[qb0 + 1][k] * vv;
    a2 += Ps[qb0 + 2][k] * vv;
  }
  float* cr = ctx + (size_t)(b * 192 + q0 + qb0) * 768 + n * 96 + d;
  cr[0] = a0; cr[768] = a1; cr[1536] = a2;
}

// ================= out = LayerNorm(xin + dres) * g + b =================
__global__ __launch_bounds__(256) void ln_kernel(const float* __restrict__ xin,
    const float* __restrict__ dres, const float* __restrict__ g,
    const float* __restrict__ bta, float* __restrict__ out) {
  const int row = blockIdx.x;
  const int t = threadIdx.x;
  __shared__ float red[256];
  const size_t base = (size_t)row * HH;
  const float v0 = xin[base + t] + dres[base + t];
  const float v1 = xin[base + 256 + t] + dres[base + 256 + t];
  const float v2 = xin[base + 512 + t] + dres[base + 512 + t];
  red[t] = v0 + v1 + v2; __syncthreads();
  for (int s = 128; s > 0; s >>= 1) { if (t < s) red[t] += red[t + s]; __syncthreads(); }
  const float mean = red[0] * (1.f / 768.f); __syncthreads();
  red[t] = v0 * v0 + v1 * v1 + v2 * v2; __syncthreads();
  for (int s = 128; s > 0; s >>= 1) { if (t < s) red[t] += red[t + s]; __syncthreads(); }
  const float var = red[0] * (1.f / 768.f) - mean * mean;
  const float rstd = rsqrtf(var + 1e-5f);
  out[base + t]       = (v0 - mean) * rstd * g[t]       + bta[t];
  out[base + 256 + t] = (v1 - mean) * rstd * g[256 + t] + bta[256 + t];
  out[base + 512 + t] = (v2 - mean) * rstd * g[512 + t] + bta[512 + t];
}

extern "C" void kernel_launch(void* const* d_in, const int* in_sizes, int n_in,
                              void* d_out, int out_size, void* d_ws, size_t ws_size,
                              hipStream_t stream) {
  const float* we      = (const float*)d_in[0];
  const float* be      = (const float*)d_in[1];
  const int*   seq_len = (const int*)d_in[2];
  const int*   lex_num = (const int*)d_in[3];
  const int*   pos_s   = (const int*)d_in[4];
  const int*   pos_e   = (const int*)d_in[5];
  const float* pe      = (const float*)d_in[6];
  const float* Wf1     = (const float*)d_in[7];
  const float* bf1     = (const float*)d_in[8];
  const float* Wf2     = (const float*)d_in[9];
  const float* bf2     = (const float*)d_in[10];
  const float* Wq = (const float*)d_in[11]; const float* bq = (const float*)d_in[12];
  const float* Wk = (const float*)d_in[13]; const float* bk = (const float*)d_in[14];
  const float* Wv = (const float*)d_in[15]; const float* bv = (const float*)d_in[16];
  const float* Wr = (const float*)d_in[17]; const float* br = (const float*)d_in[18];
  const float* uu = (const float*)d_in[19]; const float* vv = (const float*)d_in[20];
  const float* Wo = (const float*)d_in[21]; const float* bo = (const float*)d_in[22];
  const float* g1 = (const float*)d_in[23]; const float* be1 = (const float*)d_in[24];
  const float* W1 = (const float*)d_in[25]; const float* b1 = (const float*)d_in[26];
  const float* W2 = (const float*)d_in[27]; const float* b2 = (const float*)d_in[28];
  const float* g2 = (const float*)d_in[29]; const float* be2 = (const float*)d_in[30];

  // workspace layout (bytes, 16B aligned)
  char* ws = (char*)d_ws;
  float*  xb    = (float*)(ws + 0);          // [384,768]
  float*  qkv   = (float*)(ws + 1179648);    // [384,2304]
  float*  PRb   = (float*)(ws + 4718592);    // [383,768]
  __half* Tt    = (__half*)(ws + 5898240);   // [4,384,3072] f16
  __half* BTf1  = (__half*)(ws + 15335424);  // [4,3072,768] f16, dead after gemm_batch:
  float*  G     = (float*)(ws + 15335424);   //   [2,8,192,384]
  float*  parti = (float*)(ws + 20054016);   //   [4,73728,4]
  __half* P     = (__half*)(ws + 25952256);  //   [2,8,192,192] f16
  float*  ctx   = (float*)(ws + 27131904);   //   [384,768]
  float*  ao    = (float*)(ws + 28311552);   //   [384,768]
  float*  x1    = (float*)(ws + 29491200);   //   [384,768]
  float*  ff    = (float*)(ws + 30670848);   //   [384,768]
  float*  fo    = (float*)(ws + 31850496);   //   [384,768] (ends 33030144)
  __half* BTsq  = (__half*)(ws + 34209792);  // [7,768,768] f16: Wq,Wk,Wv,Wo,W1,W2,Wr
  h2*     wf2pG = (h2*)(ws + 42467328);
  h2*     bf1pG = (h2*)(ws + 42491904);
  float*  bqkv  = (float*)(ws + 42498048);   // [2304]
  float*  out   = (float*)d_out;

  const float* peu = pe + (size_t)JOFF * HH;
  const size_t SQ = (size_t)HH * HH;
  __half* WoT = BTsq + 3 * SQ; __half* W1T = BTsq + 4 * SQ;
  __half* W2T = BTsq + 5 * SQ; __half* WrT = BTsq + 6 * SQ;

  // 1. prep: add + pack + trans7 + trans_cvt
  prep_kernel<<<13537, 256, 0, stream>>>((const float4*)we, (const float4*)be, (float4*)xb,
      Wf2, bf1, bq, bk, bv, wf2pG, bf1pG, bqkv,
      Wq, Wk, Wv, Wo, W1, W2, Wr, BTsq, Wf1, BTf1);
  // 2. batched GEMM: PRb + 4xT + qkv (512-thread 8-wave blocks)
  gemm_batch<<<360, 512, 0, stream>>>(peu, WrT, br, PRb, BTf1, Tt, xb, BTsq, bqkv, qkv);
  // 3. G precompute
  g2_kernel<<<128, 256, 0, stream>>>(qkv, PRb, vv, G);
  // 4. pairA
  pairA_kernel<<<4608, 256, 0, stream>>>((const h2*)Tt, (const h8*)wf2pG, bf1pG,
      pos_s, pos_e, parti);
  // 5. attn3 (512 blocks, 1 wave per q row)
  attn3_kernel<<<512, 384, 0, stream>>>(qkv, uu, G, (const float4*)parti, bf2,
      pos_s, pos_e, seq_len, lex_num, P);
  // 6. ctx3 (256 blocks)
  ctx3_kernel<<<256, 384, 0, stream>>>(P, qkv, ctx);
  // 7-11. out-proj, LN1, FFN, LN2
  mfma_gemm<false, false><<<dim3(6, 3), 512, 0, stream>>>(ctx, WoT, bo, ao, BB * SS, HH, HH);
  ln_kernel<<<BB * SS, 256, 0, stream>>>(xb, ao, g1, be1, x1);
  mfma_gemm<false, true><<<dim3(6, 3), 512, 0, stream>>>(x1, W1T, b1, ff, BB * SS, HH, HH);
  mfma_gemm<false, false><<<dim3(6, 3), 512, 0, stream>>>(ff, W2T, b2, fo, BB * SS, HH, HH);
  ln_kernel<<<BB * SS, 256, 0, stream>>>(x1, fo, g2, be2, out);
}